// Round 7
// baseline (244.048 us; speedup 1.0000x reference)
//
#include <hip/hip_runtime.h>
#include <hip/hip_bf16.h>
#include <math.h>

#define BB 4
#define TT 2048
#define CC 768
#define NHD 16
#define HD 48
#define NQT 32  // TT/64

typedef __hip_bfloat16 bf16;
typedef __attribute__((ext_vector_type(8))) short short8;
typedef __attribute__((ext_vector_type(4))) float floatx4;

__device__ __forceinline__ unsigned short f2bf(float x) {
    bf16 h = __float2bfloat16(x);
    return *(unsigned short*)&h;
}
__device__ __forceinline__ float bfu2f(unsigned short u) {
    return __uint_as_float(((unsigned)u) << 16);
}

// async global->LDS, 16B per lane; LDS dest = wave-uniform base + lane*16
__device__ __forceinline__ void gl_lds16(const void* g, void* s) {
    __builtin_amdgcn_global_load_lds((const __attribute__((address_space(1))) void*)g,
                                     (__attribute__((address_space(3))) void*)s, 16, 0, 0);
}

// pack two fp32 -> packed bf16 pair (round-half-up; kept for GEMM path)
__device__ __forceinline__ unsigned int pk_bf2(float a, float b) {
    unsigned int ua = __float_as_uint(a) + 0x8000u;
    unsigned int ub = __float_as_uint(b) + 0x8000u;
    return __builtin_amdgcn_perm(ub, ua, 0x07060302);
}

// single-instruction packed f32x2 -> bf16x2 (D.lo = cvt(S0), D.hi = cvt(S1))
__device__ __forceinline__ unsigned int cvtpk(float lo, float hi) {
    unsigned int r;
    asm("v_cvt_pk_bf16_f32 %0, %1, %2" : "=v"(r) : "v"(lo), "v"(hi));
    return r;
}

// hot-loop barrier: make LDS writes visible, do NOT drain vmcnt -- register
// global loads (K/V prefetch) stay in flight across the barrier.
#define HOT_BARRIER() asm volatile("s_waitcnt lgkmcnt(0)\n\ts_barrier" ::: "memory")

// ---------- fp32 -> bf16 casts ----------
__global__ __launch_bounds__(256) void cast_hs(const float* __restrict__ src,
                                               unsigned short* __restrict__ dst) {
    int i = (blockIdx.x * 256 + threadIdx.x) * 4;
    float4 v = *(const float4*)(src + i);
    ushort4 p;
    p.x = f2bf(v.x); p.y = f2bf(v.y); p.z = f2bf(v.z); p.w = f2bf(v.w);
    *(ushort4*)(dst + i) = p;
}

__global__ __launch_bounds__(256) void cast_w4(const float* __restrict__ s0, const float* __restrict__ s1,
                                               const float* __restrict__ s2, const float* __restrict__ s3,
                                               unsigned short* __restrict__ d0, unsigned short* __restrict__ d1,
                                               unsigned short* __restrict__ d2, unsigned short* __restrict__ d3) {
    const float* s; unsigned short* d;
    switch (blockIdx.y) {
        case 0: s = s0; d = d0; break;
        case 1: s = s1; d = d1; break;
        case 2: s = s2; d = d2; break;
        default: s = s3; d = d3; break;
    }
    int i = (blockIdx.x * 256 + threadIdx.x) * 4;
    float4 v = *(const float4*)(s + i);
    ushort4 p;
    p.x = f2bf(v.x); p.y = f2bf(v.y); p.z = f2bf(v.z); p.w = f2bf(v.w);
    *(ushort4*)(d + i) = p;
}

// ---------- RoPE sincos table: tab[t][p] = {cos, sin}, p in [0,24) ----------
__global__ __launch_bounds__(256) void rope_table(float2* __restrict__ tab) {
    int idx = blockIdx.x * 256 + threadIdx.x;  // over 2048*24
    int t = idx / 24, p = idx % 24;
    float inv_freq = powf(10000.0f, -((float)(2 * p) / (float)HD));
    float ang = (float)t * inv_freq;
    float sn, cs;
    sincosf(ang, &sn, &cs);
    tab[idx] = make_float2(cs, sn);
}

// ---------- bf16 MFMA NT-GEMM, BK=64, lds-direct staging with XOR-swizzle ----------
template <int MODE>
__global__ __launch_bounds__(256) void gemm_mfma(const unsigned short* __restrict__ A,
                                                 const unsigned short* __restrict__ Bw,
                                                 const float* __restrict__ b0p,
                                                 const float* __restrict__ b1p,
                                                 const float* __restrict__ b2p,
                                                 void* __restrict__ out0,
                                                 void* __restrict__ out1,
                                                 void* __restrict__ out2) {
    __shared__ __align__(16) unsigned short As[128][64];
    __shared__ __align__(16) unsigned short Bs[128][64];
    const int tid = threadIdx.x;
    const int w = tid >> 6, lane = tid & 63;
    const int quad = lane >> 4, ln = lane & 15;
    const int wr = w >> 1, wc = w & 1;

    const int NXB = (MODE == 1) ? 18 : 6;
    const int bx = blockIdx.x;
    const int xcd = bx & 7, slot = bx >> 3;
    const int n0 = (slot % NXB) * 128;
    const int m0 = ((slot / NXB) * 8 + xcd) * 128;

    const int srow = lane >> 3;
    const int ssw = ((lane & 7) ^ srow) * 8;
    const unsigned short* agp[4];
    const unsigned short* bgp[4];
    void* asl[4];
    void* bsl[4];
#pragma unroll
    for (int i = 0; i < 4; ++i) {
        const int R = i * 32 + w * 8;
        agp[i] = A + (size_t)(m0 + R + srow) * CC + ssw;
        bgp[i] = Bw + (size_t)(n0 + R + srow) * CC + ssw;
        asl[i] = &As[R][0];
        bsl[i] = &Bs[R][0];
    }

    floatx4 acc[4][4];
#pragma unroll
    for (int mi = 0; mi < 4; ++mi)
#pragma unroll
        for (int ni = 0; ni < 4; ++ni) acc[mi][ni] = (floatx4){0.f, 0.f, 0.f, 0.f};

    const int ps0 = (quad ^ (ln & 7)) * 8;

    for (int k0 = 0; k0 < CC; k0 += 64) {
        __syncthreads();
#pragma unroll
        for (int i = 0; i < 4; ++i) {
            gl_lds16(agp[i] + k0, asl[i]);
            gl_lds16(bgp[i] + k0, bsl[i]);
        }
        __syncthreads();
#pragma unroll
        for (int kh = 0; kh < 2; ++kh) {
            const int ps = ps0 ^ (kh * 32);
            short8 af[4], bfr[4];
#pragma unroll
            for (int mi = 0; mi < 4; ++mi)
                af[mi] = *(const short8*)&As[wr * 64 + mi * 16 + ln][ps];
#pragma unroll
            for (int ni = 0; ni < 4; ++ni)
                bfr[ni] = *(const short8*)&Bs[wc * 64 + ni * 16 + ln][ps];
#pragma unroll
            for (int mi = 0; mi < 4; ++mi)
#pragma unroll
                for (int ni = 0; ni < 4; ++ni)
                    acc[mi][ni] = __builtin_amdgcn_mfma_f32_16x16x32_bf16(af[mi], bfr[ni], acc[mi][ni], 0, 0, 0);
        }
    }

    if (MODE == 0) {
        float* outf = (float*)out0;
        float bv[4];
#pragma unroll
        for (int ni = 0; ni < 4; ++ni) bv[ni] = b0p[n0 + wc * 64 + ni * 16 + ln];
#pragma unroll
        for (int mi = 0; mi < 4; ++mi)
#pragma unroll
            for (int r = 0; r < 4; ++r) {
                size_t row = m0 + wr * 64 + mi * 16 + quad * 4 + r;
#pragma unroll
                for (int ni = 0; ni < 4; ++ni)
                    outf[row * CC + n0 + wc * 64 + ni * 16 + ln] = acc[mi][ni][r] + bv[ni];
            }
    } else {
        const int seg = n0 / CC;
        const int nl0 = n0 - seg * CC;
        const float* bp = (seg == 0) ? b0p : (seg == 1) ? b1p : b2p;
        float bv[4];
#pragma unroll
        for (int ni = 0; ni < 4; ++ni) bv[ni] = bp[nl0 + wc * 64 + ni * 16 + ln];

        if (seg < 2) {
            unsigned short* outb = (unsigned short*)(seg == 0 ? out0 : out1);
#pragma unroll
            for (int mi = 0; mi < 4; ++mi)
#pragma unroll
                for (int r = 0; r < 4; ++r) {
                    size_t row = m0 + wr * 64 + mi * 16 + quad * 4 + r;
#pragma unroll
                    for (int ni = 0; ni < 4; ++ni)
                        outb[row * CC + nl0 + wc * 64 + ni * 16 + ln] = f2bf(acc[mi][ni][r] + bv[ni]);
                }
        } else {
            unsigned short* outb = (unsigned short*)out2;
            const int b = m0 >> 11;
#pragma unroll
            for (int ni = 0; ni < 4; ++ni) {
                int col = nl0 + wc * 64 + ni * 16 + ln;
                int h = col / HD, d = col % HD;
                size_t base = (size_t)((b * NHD + h) * HD + d) * TT;
#pragma unroll
                for (int mi = 0; mi < 4; ++mi) {
                    int t = (m0 & 2047) + wr * 64 + mi * 16 + quad * 4;
                    ushort4 pk;
                    pk.x = f2bf(acc[mi][ni][0] + bv[ni]);
                    pk.y = f2bf(acc[mi][ni][1] + bv[ni]);
                    pk.z = f2bf(acc[mi][ni][2] + bv[ni]);
                    pk.w = f2bf(acc[mi][ni][3] + bv[ni]);
                    *(ushort4*)(outb + base + t) = pk;
                }
            }
        }
    }
}

// RoPE in-place via precomputed table, vectorized (8 pairs/thread).
__global__ __launch_bounds__(256) void rope_bf(unsigned short* __restrict__ q,
                                               unsigned short* __restrict__ k,
                                               const float2* __restrict__ tab) {
    int idx = blockIdx.x * blockDim.x + threadIdx.x;  // over B*T*H*3
    const int HALF = HD / 2;
    int p8 = idx % 3;
    int rest = idx / 3;
    int h = rest % NHD;
    int n = rest / NHD;        // b*T + t
    int t = n & (TT - 1);
    const float QSC = 0.14433756729740643f * 1.4426950408889634f;
    size_t base = (size_t)n * CC + h * HD + p8 * 8;
    const float2* tp = tab + t * HALF + p8 * 8;

    short8 q1 = *(const short8*)(q + base);
    short8 q2 = *(const short8*)(q + base + HALF);
    short8 k1 = *(const short8*)(k + base);
    short8 k2 = *(const short8*)(k + base + HALF);
    short8 r1, r2, s1, s2;
#pragma unroll
    for (int jj = 0; jj < 8; ++jj) {
        float2 cssn = tp[jj];
        float cs = cssn.x, sn = cssn.y;
        float a = bfu2f((unsigned short)q1[jj]), bb = bfu2f((unsigned short)q2[jj]);
        r1[jj] = (short)f2bf((a * cs - bb * sn) * QSC);
        r2[jj] = (short)f2bf((bb * cs + a * sn) * QSC);
        float c2 = bfu2f((unsigned short)k1[jj]), d2 = bfu2f((unsigned short)k2[jj]);
        s1[jj] = (short)f2bf(c2 * cs - d2 * sn);
        s2[jj] = (short)f2bf(d2 * cs + c2 * sn);
    }
    *(short8*)(q + base) = r1;
    *(short8*)(q + base + HALF) = r2;
    *(short8*)(k + base) = s1;
    *(short8*)(k + base + HALF) = s2;
}

// MFMA flash attention, exp2-domain, fixed softmax reference (m=0).
// Round-7 structure = round-6 (128-thread blocks, 64-row q-tiles, balanced
// pair schedule, K in swizzled LDS with mask column, cvt_pk softmax pack)
// with V REMOVED FROM LDS: the 6 V fragments (wave-invariant, L2-resident --
// per-XCD K+V working set 3.6MB < 4MB) load directly from global into
// registers ONE FULL ITERATION AHEAD (consume-then-reload; V(kt+1) issued
// after PV(kt), so it has the whole next QK+softmax phase of slack and no
// wait ever drains the K prefetch). DS ops per wave-step: 33 -> 24 (-27%)
// -- attacking the measured LDS-port wall (R4/R6 both converge at
// 15-16 cyc/q-row with MfmaUtil ~24%, VALU ~28%, LDS ~85%).
__global__ __launch_bounds__(128, 2) void attn_kernel(const unsigned short* __restrict__ qb,
                                                      const unsigned short* __restrict__ kb,
                                                      const unsigned short* __restrict__ vt,
                                                      const float* __restrict__ amask,
                                                      unsigned short* __restrict__ ctx) {
    const int bx = blockIdx.x;
    const int xcd = bx & 7;
    const int s = bx >> 3;              // [0,128)
    const int bh_l = s & 7;             // 8 (b,h) per XCD
    const int pairidx = s >> 3;         // [0,16)
    const int j = (bh_l << 3) | xcd;    // (b,h) pinned per XCD
    const int b = j >> 4, h = j & 15;
    const int tid = threadIdx.x;        // [0,128)
    const int w = tid >> 6, lane = tid & 63;
    const int g = lane >> 4, ln = lane & 15;
    const int sw = ln & 7;

    __shared__ __align__(16) unsigned short Ks[64][64];
    __shared__ __align__(16) unsigned short Pw[2][32][64];
    __shared__ __align__(16) float l_s[2][32];

    const short8 z8 = {0, 0, 0, 0, 0, 0, 0, 0};
    const short8 ones8 = {0x3F80, 0x3F80, 0x3F80, 0x3F80, 0x3F80, 0x3F80, 0x3F80, 0x3F80};

    // zero Ks pad units 6,7 (XOR-swizzled) once; unit-6 elem 0 = mask slot
    // (rewritten each step), elems 1..7 and unit 7 stay 0.
    {
        int rr = tid & 63, half = tid >> 6;
        *(short8*)&Ks[rr][((6 + half) ^ (rr & 7)) * 8] = z8;
    }

    // K staging: 64 rows x 6 units, 3 units per thread
    const int u0 = tid, u1 = tid + 128, u2 = tid + 256;
    const int rK0 = u0 / 6, sK0 = u0 % 6;
    const int rK1 = u1 / 6, sK1 = u1 % 6;
    const int rK2 = u2 / 6, sK2 = u2 % 6;
    unsigned short* dK0 = &Ks[rK0][(sK0 ^ (rK0 & 7)) * 8];
    unsigned short* dK1 = &Ks[rK1][(sK1 ^ (rK1 & 7)) * 8];
    unsigned short* dK2 = &Ks[rK2][(sK2 ^ (rK2 & 7)) * 8];
    const unsigned short* kbase0 = kb + (size_t)(b * TT + rK0) * CC + h * HD + sK0 * 8;
    const unsigned short* kbase1 = kb + (size_t)(b * TT + rK1) * CC + h * HD + sK1 * 8;
    const unsigned short* kbase2 = kb + (size_t)(b * TT + rK2) * CC + h * HD + sK2 * 8;
    const float* mbase = amask + b * TT + (tid & 63);
    const float MBS = -10000.0f * 1.4426950408889634f;
    const int mcol = (6 ^ (tid & 7)) * 8;        // swizzled mask slot, row = tid (<64)
    const short8 vone = (ln == 0) ? ones8 : z8;  // ones-column B-frag (l accumulator)
    const int rowA = w * 32 + ln;                // tile-local q-row of group a

    // V fragment bases (direct global, per-lane): frag n row = n*16+ln of
    // [B,H,D,T]-transposed V; cols k0 + g*8 (lo) / +32 (hi). Wave-invariant.
    const unsigned short* vfb0 = vt + ((size_t)((b * NHD + h) * HD) + 0 * 16 + ln) * TT + g * 8;
    const unsigned short* vfb1 = vt + ((size_t)((b * NHD + h) * HD) + 1 * 16 + ln) * TT + g * 8;
    const unsigned short* vfb2 = vt + ((size_t)((b * NHD + h) * HD) + 2 * 16 + ln) * TT + g * 8;

    for (int rep = 0; rep < 2; ++rep) {
        const int qt = rep ? (NQT - 1 - pairidx) : pairidx;   // steps = qt+1
        const int q0 = qt * 64;

        // Q fragments straight from global; mask column (48) pairs with the
        // constant {1.0,0...} element on the g==2 quad of aq1.
        const unsigned short* qrA = qb + (size_t)(b * TT + q0 + w * 32 + ln) * CC + h * HD;
        const unsigned short* qrB = qrA + (size_t)16 * CC;
        short8 aq0a = *(const short8*)(qrA + g * 8);
        short8 aq0b = *(const short8*)(qrB + g * 8);
        short8 aq1a, aq1b;
        if (g < 2) {
            aq1a = *(const short8*)(qrA + 32 + g * 8);
            aq1b = *(const short8*)(qrB + 32 + g * 8);
        } else {
            aq1a = z8; aq1b = z8;
            if (g == 2) { aq1a[0] = (short)0x3F80; aq1b[0] = (short)0x3F80; }
        }

        const unsigned short* kp0 = kbase0;
        const unsigned short* kp1 = kbase1;
        const unsigned short* kp2 = kbase2;
        const unsigned short* vp0 = vfb0;
        const unsigned short* vp1 = vfb1;
        const unsigned short* vp2 = vfb2;
        const float* mp = mbase;

        short8 kr0 = *(const short8*)kp0;
        short8 kr1 = *(const short8*)kp1;
        short8 kr2 = *(const short8*)kp2;
        float mr = (tid < 64) ? *mp : 1.0f;
        // V(0) fragments into registers (consumed at kt=0's PV)
        short8 vc00 = *(const short8*)vp0;
        short8 vc01 = *(const short8*)(vp0 + 32);
        short8 vc10 = *(const short8*)vp1;
        short8 vc11 = *(const short8*)(vp1 + 32);
        short8 vc20 = *(const short8*)vp2;
        short8 vc21 = *(const short8*)(vp2 + 32);

        floatx4 oa0 = {0.f, 0.f, 0.f, 0.f}, oa1 = oa0, oa2 = oa0, oa3 = oa0;
        floatx4 ob0 = oa0, ob1 = oa0, ob2 = oa0, ob3 = oa0;

        for (int kt = 0; kt <= qt; ++kt) {
            HOT_BARRIER();   // prior step's (or prior rep's) LDS reads complete
            *(short8*)dK0 = kr0; *(short8*)dK1 = kr1; *(short8*)dK2 = kr2;
            if (tid < 64) Ks[tid][mcol] = f2bf((1.0f - mr) * MBS);
            HOT_BARRIER();   // writes visible; vmcnt NOT drained

            if (kt < qt) {   // K prefetch for tile kt+1 (consumed next top)
                kp0 += (size_t)64 * CC; kr0 = *(const short8*)kp0;
                kp1 += (size_t)64 * CC; kr1 = *(const short8*)kp1;
                kp2 += (size_t)64 * CC; kr2 = *(const short8*)kp2;
                if (tid < 64) { mp += 64; mr = *mp; }
            }

            const bool masked = (kt == qt);   // wave-uniform: diag tile only

            // QK^T: each K fragment read feeds BOTH q-groups.
            floatx4 sa_[4], sb_[4];
#pragma unroll
            for (int c = 0; c < 4; ++c) {
                short8 kf0 = *(const short8*)&Ks[c * 16 + ln][(g ^ sw) * 8];
                short8 kf1 = *(const short8*)&Ks[c * 16 + ln][((4 + g) ^ sw) * 8];
                floatx4 z = {0.f, 0.f, 0.f, 0.f};
                floatx4 za = __builtin_amdgcn_mfma_f32_16x16x32_bf16(kf0, aq0a, z, 0, 0, 0);
                sa_[c] = __builtin_amdgcn_mfma_f32_16x16x32_bf16(kf1, aq1a, za, 0, 0, 0);
                floatx4 zb = __builtin_amdgcn_mfma_f32_16x16x32_bf16(kf0, aq0b, z, 0, 0, 0);
                sb_[c] = __builtin_amdgcn_mfma_f32_16x16x32_bf16(kf1, aq1b, zb, 0, 0, 0);
            }

            // softmax (exp2-domain) + pack into Pw
#pragma unroll
            for (int c = 0; c < 4; ++c) {
                float pva[4], pvb[4];
#pragma unroll
                for (int r = 0; r < 4; ++r) {
                    pva[r] = __builtin_amdgcn_exp2f(sa_[c][r]);
                    pvb[r] = __builtin_amdgcn_exp2f(sb_[c][r]);
                }
                if (masked) {   // uniform branch: only the diagonal step pays
#pragma unroll
                    for (int r = 0; r < 4; ++r) {
                        int kcol = c * 16 + g * 4 + r;
                        if (kcol > rowA) pva[r] = 0.f;
                        if (kcol > rowA + 16) pvb[r] = 0.f;
                    }
                }
                uint2 pka, pkb;
                pka.x = cvtpk(pva[0], pva[1]);
                pka.y = cvtpk(pva[2], pva[3]);
                pkb.x = cvtpk(pvb[0], pvb[1]);
                pkb.y = cvtpk(pvb[2], pvb[3]);
                *(uint2*)&Pw[w][ln][((2 * c + (g >> 1)) ^ sw) * 8 + (g & 1) * 4] = pka;
                *(uint2*)&Pw[w][16 + ln][((2 * c + (g >> 1)) ^ sw) * 8 + (g & 1) * 4] = pkb;
            }

            short8 pa0a = *(const short8*)&Pw[w][ln][(g ^ sw) * 8];
            short8 pa1a = *(const short8*)&Pw[w][ln][((4 + g) ^ sw) * 8];
            short8 pa0b = *(const short8*)&Pw[w][16 + ln][(g ^ sw) * 8];
            short8 pa1b = *(const short8*)&Pw[w][16 + ln][((4 + g) ^ sw) * 8];

            // PV: vc* fragments were loaded one full iteration ago (latency
            // hidden); each feeds BOTH q-groups.
            oa0 = __builtin_amdgcn_mfma_f32_16x16x32_bf16(pa0a, vc00, oa0, 0, 0, 0);
            oa0 = __builtin_amdgcn_mfma_f32_16x16x32_bf16(pa1a, vc01, oa0, 0, 0, 0);
            ob0 = __builtin_amdgcn_mfma_f32_16x16x32_bf16(pa0b, vc00, ob0, 0, 0, 0);
            ob0 = __builtin_amdgcn_mfma_f32_16x16x32_bf16(pa1b, vc01, ob0, 0, 0, 0);
            oa1 = __builtin_amdgcn_mfma_f32_16x16x32_bf16(pa0a, vc10, oa1, 0, 0, 0);
            oa1 = __builtin_amdgcn_mfma_f32_16x16x32_bf16(pa1a, vc11, oa1, 0, 0, 0);
            ob1 = __builtin_amdgcn_mfma_f32_16x16x32_bf16(pa0b, vc10, ob1, 0, 0, 0);
            ob1 = __builtin_amdgcn_mfma_f32_16x16x32_bf16(pa1b, vc11, ob1, 0, 0, 0);
            oa2 = __builtin_amdgcn_mfma_f32_16x16x32_bf16(pa0a, vc20, oa2, 0, 0, 0);
            oa2 = __builtin_amdgcn_mfma_f32_16x16x32_bf16(pa1a, vc21, oa2, 0, 0, 0);
            ob2 = __builtin_amdgcn_mfma_f32_16x16x32_bf16(pa0b, vc20, ob2, 0, 0, 0);
            ob2 = __builtin_amdgcn_mfma_f32_16x16x32_bf16(pa1b, vc21, ob2, 0, 0, 0);
            oa3 = __builtin_amdgcn_mfma_f32_16x16x32_bf16(pa0a, vone, oa3, 0, 0, 0);
            oa3 = __builtin_amdgcn_mfma_f32_16x16x32_bf16(pa1a, vone, oa3, 0, 0, 0);
            ob3 = __builtin_amdgcn_mfma_f32_16x16x32_bf16(pa0b, vone, ob3, 0, 0, 0);
            ob3 = __builtin_amdgcn_mfma_f32_16x16x32_bf16(pa1b, vone, ob3, 0, 0, 0);

            if (kt < qt) {   // V prefetch for tile kt+1 (consumed next PV)
                vp0 += 64; vp1 += 64; vp2 += 64;
                vc00 = *(const short8*)vp0; vc01 = *(const short8*)(vp0 + 32);
                vc10 = *(const short8*)vp1; vc11 = *(const short8*)(vp1 + 32);
                vc20 = *(const short8*)vp2; vc21 = *(const short8*)(vp2 + 32);
            }
        }

        if (ln == 0) {                               // per-wave region, no barrier
            *(floatx4*)&l_s[w][g * 4] = oa3;
            *(floatx4*)&l_s[w][16 + g * 4] = ob3;
        }
        floatx4 l4a = *(const floatx4*)&l_s[w][g * 4];
        floatx4 l4b = *(const floatx4*)&l_s[w][16 + g * 4];
#pragma unroll
        for (int r = 0; r < 4; ++r) {
            float invA = 1.0f / l4a[r];
            int t = q0 + w * 32 + g * 4 + r;
            unsigned short* dst = ctx + (size_t)(b * TT + t) * CC + h * HD;
            dst[ln] = f2bf(oa0[r] * invA);
            dst[16 + ln] = f2bf(oa1[r] * invA);
            dst[32 + ln] = f2bf(oa2[r] * invA);
            float invB = 1.0f / l4b[r];
            unsigned short* dstB = dst + (size_t)16 * CC;
            dstB[ln] = f2bf(ob0[r] * invB);
            dstB[16 + ln] = f2bf(ob1[r] * invB);
            dstB[32 + ln] = f2bf(ob2[r] * invB);
        }
    }
}

extern "C" void kernel_launch(void* const* d_in, const int* in_sizes, int n_in,
                              void* d_out, int out_size, void* d_ws, size_t ws_size,
                              hipStream_t stream) {
    const float* hs = (const float*)d_in[0];
    const float* amask = (const float*)d_in[1];
    const float* Wq = (const float*)d_in[2];
    const float* bq = (const float*)d_in[3];
    const float* Wk = (const float*)d_in[4];
    const float* bk = (const float*)d_in[5];
    const float* Wv = (const float*)d_in[6];
    const float* bv = (const float*)d_in[7];
    const float* Wo = (const float*)d_in[8];
    const float* bo = (const float*)d_in[9];

    const size_t NELEM = (size_t)BB * TT * CC;  // 6291456
    const size_t WELEM = (size_t)CC * CC;       // 589824
    unsigned short* hb  = (unsigned short*)d_ws;
    unsigned short* qbuf = hb + NELEM;
    unsigned short* kbuf = qbuf + NELEM;
    unsigned short* vtb = kbuf + NELEM;   // bf16 [B,H,D,T]
    unsigned short* ctxb = vtb + NELEM;
    unsigned short* wqb = ctxb + NELEM;   // wq/wk/wv contiguous = stacked [2304][768]
    unsigned short* wkb = wqb + WELEM;
    unsigned short* wvb = wkb + WELEM;
    unsigned short* wob = wvb + WELEM;
    float2* ropetab = (float2*)(wob + WELEM);  // [2048][24]

    cast_hs<<<NELEM / 1024, 256, 0, stream>>>(hs, hb);
    dim3 wgrid(WELEM / 1024, 4);
    cast_w4<<<wgrid, 256, 0, stream>>>(Wq, Wk, Wv, Wo, wqb, wkb, wvb, wob);
    rope_table<<<(TT * (HD / 2)) / 256, 256, 0, stream>>>(ropetab);

    gemm_mfma<1><<<18 * 64, 256, 0, stream>>>(hb, wqb, bq, bk, bv, qbuf, kbuf, vtb);

    int rope_total = BB * TT * NHD * 3;  // 8 pairs per thread
    rope_bf<<<rope_total / 256, 256, 0, stream>>>(qbuf, kbuf, ropetab);

    attn_kernel<<<1024, 128, 0, stream>>>(qbuf, kbuf, vtb, amask, ctxb);

    gemm_mfma<0><<<6 * 64, 256, 0, stream>>>(ctxb, wob, bo, nullptr, nullptr,
                                             (float*)d_out, nullptr, nullptr);
}

// Round 8
// 223.862 us; speedup vs baseline: 1.0902x; 1.0902x over previous
//
#include <hip/hip_runtime.h>
#include <hip/hip_bf16.h>
#include <math.h>

#define BB 4
#define TT 2048
#define CC 768
#define NHD 16
#define HD 48
#define NQT 32  // TT/64

typedef __hip_bfloat16 bf16;
typedef __attribute__((ext_vector_type(8))) short short8;
typedef __attribute__((ext_vector_type(4))) float floatx4;

__device__ __forceinline__ unsigned short f2bf(float x) {
    bf16 h = __float2bfloat16(x);
    return *(unsigned short*)&h;
}
__device__ __forceinline__ float bfu2f(unsigned short u) {
    return __uint_as_float(((unsigned)u) << 16);
}

// async global->LDS, 16B per lane; LDS dest = wave-uniform base + lane*16
__device__ __forceinline__ void gl_lds16(const void* g, void* s) {
    __builtin_amdgcn_global_load_lds((const __attribute__((address_space(1))) void*)g,
                                     (__attribute__((address_space(3))) void*)s, 16, 0, 0);
}

// pack two fp32 -> packed bf16 pair (round-half-up; kept for GEMM path)
__device__ __forceinline__ unsigned int pk_bf2(float a, float b) {
    unsigned int ua = __float_as_uint(a) + 0x8000u;
    unsigned int ub = __float_as_uint(b) + 0x8000u;
    return __builtin_amdgcn_perm(ub, ua, 0x07060302);
}

// single-instruction packed f32x2 -> bf16x2 (D.lo = cvt(S0), D.hi = cvt(S1))
__device__ __forceinline__ unsigned int cvtpk(float lo, float hi) {
    unsigned int r;
    asm("v_cvt_pk_bf16_f32 %0, %1, %2" : "=v"(r) : "v"(lo), "v"(hi));
    return r;
}

// hot-loop barrier: make LDS writes visible, do NOT drain vmcnt -- register
// global loads (K/V prefetch) stay in flight across the barrier.
#define HOT_BARRIER() asm volatile("s_waitcnt lgkmcnt(0)\n\ts_barrier" ::: "memory")

// ---------- fp32 -> bf16 casts ----------
__global__ __launch_bounds__(256) void cast_hs(const float* __restrict__ src,
                                               unsigned short* __restrict__ dst) {
    int i = (blockIdx.x * 256 + threadIdx.x) * 4;
    float4 v = *(const float4*)(src + i);
    ushort4 p;
    p.x = f2bf(v.x); p.y = f2bf(v.y); p.z = f2bf(v.z); p.w = f2bf(v.w);
    *(ushort4*)(dst + i) = p;
}

__global__ __launch_bounds__(256) void cast_w4(const float* __restrict__ s0, const float* __restrict__ s1,
                                               const float* __restrict__ s2, const float* __restrict__ s3,
                                               unsigned short* __restrict__ d0, unsigned short* __restrict__ d1,
                                               unsigned short* __restrict__ d2, unsigned short* __restrict__ d3) {
    const float* s; unsigned short* d;
    switch (blockIdx.y) {
        case 0: s = s0; d = d0; break;
        case 1: s = s1; d = d1; break;
        case 2: s = s2; d = d2; break;
        default: s = s3; d = d3; break;
    }
    int i = (blockIdx.x * 256 + threadIdx.x) * 4;
    float4 v = *(const float4*)(s + i);
    ushort4 p;
    p.x = f2bf(v.x); p.y = f2bf(v.y); p.z = f2bf(v.z); p.w = f2bf(v.w);
    *(ushort4*)(d + i) = p;
}

// ---------- RoPE sincos table: tab[t][p] = {cos, sin}, p in [0,24) ----------
__global__ __launch_bounds__(256) void rope_table(float2* __restrict__ tab) {
    int idx = blockIdx.x * 256 + threadIdx.x;  // over 2048*24
    int t = idx / 24, p = idx % 24;
    float inv_freq = powf(10000.0f, -((float)(2 * p) / (float)HD));
    float ang = (float)t * inv_freq;
    float sn, cs;
    sincosf(ang, &sn, &cs);
    tab[idx] = make_float2(cs, sn);
}

// ---------- bf16 MFMA NT-GEMM, BK=64, lds-direct staging with XOR-swizzle ----------
template <int MODE>
__global__ __launch_bounds__(256) void gemm_mfma(const unsigned short* __restrict__ A,
                                                 const unsigned short* __restrict__ Bw,
                                                 const float* __restrict__ b0p,
                                                 const float* __restrict__ b1p,
                                                 const float* __restrict__ b2p,
                                                 void* __restrict__ out0,
                                                 void* __restrict__ out1,
                                                 void* __restrict__ out2) {
    __shared__ __align__(16) unsigned short As[128][64];
    __shared__ __align__(16) unsigned short Bs[128][64];
    const int tid = threadIdx.x;
    const int w = tid >> 6, lane = tid & 63;
    const int quad = lane >> 4, ln = lane & 15;
    const int wr = w >> 1, wc = w & 1;

    const int NXB = (MODE == 1) ? 18 : 6;
    const int bx = blockIdx.x;
    const int xcd = bx & 7, slot = bx >> 3;
    const int n0 = (slot % NXB) * 128;
    const int m0 = ((slot / NXB) * 8 + xcd) * 128;

    const int srow = lane >> 3;
    const int ssw = ((lane & 7) ^ srow) * 8;
    const unsigned short* agp[4];
    const unsigned short* bgp[4];
    void* asl[4];
    void* bsl[4];
#pragma unroll
    for (int i = 0; i < 4; ++i) {
        const int R = i * 32 + w * 8;
        agp[i] = A + (size_t)(m0 + R + srow) * CC + ssw;
        bgp[i] = Bw + (size_t)(n0 + R + srow) * CC + ssw;
        asl[i] = &As[R][0];
        bsl[i] = &Bs[R][0];
    }

    floatx4 acc[4][4];
#pragma unroll
    for (int mi = 0; mi < 4; ++mi)
#pragma unroll
        for (int ni = 0; ni < 4; ++ni) acc[mi][ni] = (floatx4){0.f, 0.f, 0.f, 0.f};

    const int ps0 = (quad ^ (ln & 7)) * 8;

    for (int k0 = 0; k0 < CC; k0 += 64) {
        __syncthreads();
#pragma unroll
        for (int i = 0; i < 4; ++i) {
            gl_lds16(agp[i] + k0, asl[i]);
            gl_lds16(bgp[i] + k0, bsl[i]);
        }
        __syncthreads();
#pragma unroll
        for (int kh = 0; kh < 2; ++kh) {
            const int ps = ps0 ^ (kh * 32);
            short8 af[4], bfr[4];
#pragma unroll
            for (int mi = 0; mi < 4; ++mi)
                af[mi] = *(const short8*)&As[wr * 64 + mi * 16 + ln][ps];
#pragma unroll
            for (int ni = 0; ni < 4; ++ni)
                bfr[ni] = *(const short8*)&Bs[wc * 64 + ni * 16 + ln][ps];
#pragma unroll
            for (int mi = 0; mi < 4; ++mi)
#pragma unroll
                for (int ni = 0; ni < 4; ++ni)
                    acc[mi][ni] = __builtin_amdgcn_mfma_f32_16x16x32_bf16(af[mi], bfr[ni], acc[mi][ni], 0, 0, 0);
        }
    }

    if (MODE == 0) {
        float* outf = (float*)out0;
        float bv[4];
#pragma unroll
        for (int ni = 0; ni < 4; ++ni) bv[ni] = b0p[n0 + wc * 64 + ni * 16 + ln];
#pragma unroll
        for (int mi = 0; mi < 4; ++mi)
#pragma unroll
            for (int r = 0; r < 4; ++r) {
                size_t row = m0 + wr * 64 + mi * 16 + quad * 4 + r;
#pragma unroll
                for (int ni = 0; ni < 4; ++ni)
                    outf[row * CC + n0 + wc * 64 + ni * 16 + ln] = acc[mi][ni][r] + bv[ni];
            }
    } else {
        const int seg = n0 / CC;
        const int nl0 = n0 - seg * CC;
        const float* bp = (seg == 0) ? b0p : (seg == 1) ? b1p : b2p;
        float bv[4];
#pragma unroll
        for (int ni = 0; ni < 4; ++ni) bv[ni] = bp[nl0 + wc * 64 + ni * 16 + ln];

        if (seg < 2) {
            unsigned short* outb = (unsigned short*)(seg == 0 ? out0 : out1);
#pragma unroll
            for (int mi = 0; mi < 4; ++mi)
#pragma unroll
                for (int r = 0; r < 4; ++r) {
                    size_t row = m0 + wr * 64 + mi * 16 + quad * 4 + r;
#pragma unroll
                    for (int ni = 0; ni < 4; ++ni)
                        outb[row * CC + nl0 + wc * 64 + ni * 16 + ln] = f2bf(acc[mi][ni][r] + bv[ni]);
                }
        } else {
            unsigned short* outb = (unsigned short*)out2;
            const int b = m0 >> 11;
#pragma unroll
            for (int ni = 0; ni < 4; ++ni) {
                int col = nl0 + wc * 64 + ni * 16 + ln;
                int h = col / HD, d = col % HD;
                size_t base = (size_t)((b * NHD + h) * HD + d) * TT;
#pragma unroll
                for (int mi = 0; mi < 4; ++mi) {
                    int t = (m0 & 2047) + wr * 64 + mi * 16 + quad * 4;
                    ushort4 pk;
                    pk.x = f2bf(acc[mi][ni][0] + bv[ni]);
                    pk.y = f2bf(acc[mi][ni][1] + bv[ni]);
                    pk.z = f2bf(acc[mi][ni][2] + bv[ni]);
                    pk.w = f2bf(acc[mi][ni][3] + bv[ni]);
                    *(ushort4*)(outb + base + t) = pk;
                }
            }
        }
    }
}

// RoPE in-place via precomputed table, vectorized (8 pairs/thread).
__global__ __launch_bounds__(256) void rope_bf(unsigned short* __restrict__ q,
                                               unsigned short* __restrict__ k,
                                               const float2* __restrict__ tab) {
    int idx = blockIdx.x * blockDim.x + threadIdx.x;  // over B*T*H*3
    const int HALF = HD / 2;
    int p8 = idx % 3;
    int rest = idx / 3;
    int h = rest % NHD;
    int n = rest / NHD;        // b*T + t
    int t = n & (TT - 1);
    const float QSC = 0.14433756729740643f * 1.4426950408889634f;
    size_t base = (size_t)n * CC + h * HD + p8 * 8;
    const float2* tp = tab + t * HALF + p8 * 8;

    short8 q1 = *(const short8*)(q + base);
    short8 q2 = *(const short8*)(q + base + HALF);
    short8 k1 = *(const short8*)(k + base);
    short8 k2 = *(const short8*)(k + base + HALF);
    short8 r1, r2, s1, s2;
#pragma unroll
    for (int jj = 0; jj < 8; ++jj) {
        float2 cssn = tp[jj];
        float cs = cssn.x, sn = cssn.y;
        float a = bfu2f((unsigned short)q1[jj]), bb = bfu2f((unsigned short)q2[jj]);
        r1[jj] = (short)f2bf((a * cs - bb * sn) * QSC);
        r2[jj] = (short)f2bf((bb * cs + a * sn) * QSC);
        float c2 = bfu2f((unsigned short)k1[jj]), d2 = bfu2f((unsigned short)k2[jj]);
        s1[jj] = (short)f2bf(c2 * cs - d2 * sn);
        s2[jj] = (short)f2bf(d2 * cs + c2 * sn);
    }
    *(short8*)(q + base) = r1;
    *(short8*)(q + base + HALF) = r2;
    *(short8*)(k + base) = s1;
    *(short8*)(k + base + HALF) = s2;
}

// MFMA flash attention, exp2-domain, fixed softmax reference (m=0).
// Round-8 structure = round-6 (128-thread blocks, 64-row q-tiles, balanced
// pair schedule grid 1024 = 4 blocks/CU, V in swizzled LDS, cvt_pk pack,
// uniform diag branch) + DOUBLE-BUFFERED K and V with ONE barrier per
// k-step. Iteration kt: {issue global prefetch(kt+1) -> compute on
// buf[kt&1] -> write regs to buf[kt&1 ^ 1] -> lgkm-barrier}. The write at
// step kt targets the buffer whose last readers finished before the
// barrier ending step kt-1, so a single barrier is race-free. R7's null
// (removing 27% of DS ops made it slower) proved the kernel is serial-
// chain-bound, not LDS-throughput-bound: this halves the per-step barrier
// count and takes staging out of the inter-barrier critical path.
__global__ __launch_bounds__(128, 2) void attn_kernel(const unsigned short* __restrict__ qb,
                                                      const unsigned short* __restrict__ kb,
                                                      const unsigned short* __restrict__ vt,
                                                      const float* __restrict__ amask,
                                                      unsigned short* __restrict__ ctx) {
    const int bx = blockIdx.x;
    const int xcd = bx & 7;
    const int s = bx >> 3;              // [0,128)
    const int bh_l = s & 7;             // 8 (b,h) per XCD
    const int pairidx = s >> 3;         // [0,16)
    const int j = (bh_l << 3) | xcd;    // (b,h) pinned per XCD
    const int b = j >> 4, h = j & 15;
    const int tid = threadIdx.x;        // [0,128)
    const int w = tid >> 6, lane = tid & 63;
    const int g = lane >> 4, ln = lane & 15;
    const int sw = ln & 7;

    __shared__ __align__(16) unsigned short Ks[2][64][64];
    __shared__ __align__(16) unsigned short Vs[2][48][64];
    __shared__ __align__(16) unsigned short Pw[2][32][64];
    __shared__ __align__(16) float l_s[2][32];

    const short8 z8 = {0, 0, 0, 0, 0, 0, 0, 0};
    const short8 ones8 = {0x3F80, 0x3F80, 0x3F80, 0x3F80, 0x3F80, 0x3F80, 0x3F80, 0x3F80};

    // zero Ks pad units 6,7 (XOR-swizzled) in BOTH buffers once; unit-6
    // elem 0 = mask slot (rewritten each step), rest stays 0. Staging only
    // touches units 0..5, so pads persist.
    {
        int rr = tid & 63, half = tid >> 6;
        *(short8*)&Ks[0][rr][((6 + half) ^ (rr & 7)) * 8] = z8;
        *(short8*)&Ks[1][rr][((6 + half) ^ (rr & 7)) * 8] = z8;
    }

    // staging: 3 K-units (64x6) and 3 V-units (48x8) per thread
    const int u0 = tid, u1 = tid + 128, u2 = tid + 256;
    const int rK0 = u0 / 6, sK0 = u0 % 6;
    const int rK1 = u1 / 6, sK1 = u1 % 6;
    const int rK2 = u2 / 6, sK2 = u2 % 6;
    const int rV0 = u0 >> 3, sV0 = u0 & 7;
    const int rV1 = u1 >> 3, sV1 = u1 & 7;
    const int rV2 = u2 >> 3, sV2 = u2 & 7;
    const int offK0 = rK0 * 64 + (sK0 ^ (rK0 & 7)) * 8;
    const int offK1 = rK1 * 64 + (sK1 ^ (rK1 & 7)) * 8;
    const int offK2 = rK2 * 64 + (sK2 ^ (rK2 & 7)) * 8;
    const int offV0 = rV0 * 64 + (sV0 ^ (rV0 & 7)) * 8;
    const int offV1 = rV1 * 64 + (sV1 ^ (rV1 & 7)) * 8;
    const int offV2 = rV2 * 64 + (sV2 ^ (rV2 & 7)) * 8;
    const int offM = (tid & 63) * 64 + (6 ^ (tid & 7)) * 8;  // mask slot, row=tid(<64)

    const unsigned short* kbase0 = kb + (size_t)(b * TT + rK0) * CC + h * HD + sK0 * 8;
    const unsigned short* kbase1 = kb + (size_t)(b * TT + rK1) * CC + h * HD + sK1 * 8;
    const unsigned short* kbase2 = kb + (size_t)(b * TT + rK2) * CC + h * HD + sK2 * 8;
    const unsigned short* vbase0 = vt + ((size_t)((b * NHD + h) * HD) + rV0) * TT + sV0 * 8;
    const unsigned short* vbase1 = vt + ((size_t)((b * NHD + h) * HD) + rV1) * TT + sV1 * 8;
    const unsigned short* vbase2 = vt + ((size_t)((b * NHD + h) * HD) + rV2) * TT + sV2 * 8;
    const float* mbase = amask + b * TT + (tid & 63);
    const float MBS = -10000.0f * 1.4426950408889634f;
    const short8 vone = (ln == 0) ? ones8 : z8;  // ones-column B-frag (l accumulator)
    const int rowA = w * 32 + ln;                // tile-local q-row of group a

    for (int rep = 0; rep < 2; ++rep) {
        const int qt = rep ? (NQT - 1 - pairidx) : pairidx;   // steps = qt+1
        const int q0 = qt * 64;

        // Q fragments straight from global; mask column (48) pairs with the
        // constant {1.0,0...} element on the g==2 quad of aq1.
        const unsigned short* qrA = qb + (size_t)(b * TT + q0 + w * 32 + ln) * CC + h * HD;
        const unsigned short* qrB = qrA + (size_t)16 * CC;
        short8 aq0a = *(const short8*)(qrA + g * 8);
        short8 aq0b = *(const short8*)(qrB + g * 8);
        short8 aq1a, aq1b;
        if (g < 2) {
            aq1a = *(const short8*)(qrA + 32 + g * 8);
            aq1b = *(const short8*)(qrB + 32 + g * 8);
        } else {
            aq1a = z8; aq1b = z8;
            if (g == 2) { aq1a[0] = (short)0x3F80; aq1b[0] = (short)0x3F80; }
        }

        const unsigned short* kp0 = kbase0;
        const unsigned short* kp1 = kbase1;
        const unsigned short* kp2 = kbase2;
        const unsigned short* vp0 = vbase0;
        const unsigned short* vp1 = vbase1;
        const unsigned short* vp2 = vbase2;
        const float* mp = mbase;

        // prologue: tile 0 -> regs -> buf0
        short8 kr0 = *(const short8*)kp0;
        short8 kr1 = *(const short8*)kp1;
        short8 kr2 = *(const short8*)kp2;
        short8 vr0 = *(const short8*)vp0;
        short8 vr1 = *(const short8*)vp1;
        short8 vr2 = *(const short8*)vp2;
        float mr = (tid < 64) ? *mp : 1.0f;

        HOT_BARRIER();   // all waves done reading any buffer (prev rep)
        {
            unsigned short* kd = &Ks[0][0][0];
            unsigned short* vd = &Vs[0][0][0];
            *(short8*)(kd + offK0) = kr0;
            *(short8*)(kd + offK1) = kr1;
            *(short8*)(kd + offK2) = kr2;
            *(short8*)(vd + offV0) = vr0;
            *(short8*)(vd + offV1) = vr1;
            *(short8*)(vd + offV2) = vr2;
            if (tid < 64) kd[offM] = f2bf((1.0f - mr) * MBS);
        }
        HOT_BARRIER();   // buf0 visible

        floatx4 oa0 = {0.f, 0.f, 0.f, 0.f}, oa1 = oa0, oa2 = oa0, oa3 = oa0;
        floatx4 ob0 = oa0, ob1 = oa0, ob2 = oa0, ob3 = oa0;

        for (int kt = 0; kt <= qt; ++kt) {
            const int buf = kt & 1;

            if (kt < qt) {   // issue global prefetch for tile kt+1 (regs)
                kp0 += (size_t)64 * CC; kr0 = *(const short8*)kp0;
                kp1 += (size_t)64 * CC; kr1 = *(const short8*)kp1;
                kp2 += (size_t)64 * CC; kr2 = *(const short8*)kp2;
                vp0 += 64; vr0 = *(const short8*)vp0;
                vp1 += 64; vr1 = *(const short8*)vp1;
                vp2 += 64; vr2 = *(const short8*)vp2;
                if (tid < 64) { mp += 64; mr = *mp; }
            }

            const bool masked = (kt == qt);   // wave-uniform: diag tile only

            // QK^T: each K fragment read feeds BOTH q-groups.
            floatx4 sa_[4], sb_[4];
#pragma unroll
            for (int c = 0; c < 4; ++c) {
                short8 kf0 = *(const short8*)&Ks[buf][c * 16 + ln][(g ^ sw) * 8];
                short8 kf1 = *(const short8*)&Ks[buf][c * 16 + ln][((4 + g) ^ sw) * 8];
                floatx4 z = {0.f, 0.f, 0.f, 0.f};
                floatx4 za = __builtin_amdgcn_mfma_f32_16x16x32_bf16(kf0, aq0a, z, 0, 0, 0);
                sa_[c] = __builtin_amdgcn_mfma_f32_16x16x32_bf16(kf1, aq1a, za, 0, 0, 0);
                floatx4 zb = __builtin_amdgcn_mfma_f32_16x16x32_bf16(kf0, aq0b, z, 0, 0, 0);
                sb_[c] = __builtin_amdgcn_mfma_f32_16x16x32_bf16(kf1, aq1b, zb, 0, 0, 0);
            }

            // softmax (exp2-domain) + pack into Pw
#pragma unroll
            for (int c = 0; c < 4; ++c) {
                float pva[4], pvb[4];
#pragma unroll
                for (int r = 0; r < 4; ++r) {
                    pva[r] = __builtin_amdgcn_exp2f(sa_[c][r]);
                    pvb[r] = __builtin_amdgcn_exp2f(sb_[c][r]);
                }
                if (masked) {   // uniform branch: only the diagonal step pays
#pragma unroll
                    for (int r = 0; r < 4; ++r) {
                        int kcol = c * 16 + g * 4 + r;
                        if (kcol > rowA) pva[r] = 0.f;
                        if (kcol > rowA + 16) pvb[r] = 0.f;
                    }
                }
                uint2 pka, pkb;
                pka.x = cvtpk(pva[0], pva[1]);
                pka.y = cvtpk(pva[2], pva[3]);
                pkb.x = cvtpk(pvb[0], pvb[1]);
                pkb.y = cvtpk(pvb[2], pvb[3]);
                *(uint2*)&Pw[w][ln][((2 * c + (g >> 1)) ^ sw) * 8 + (g & 1) * 4] = pka;
                *(uint2*)&Pw[w][16 + ln][((2 * c + (g >> 1)) ^ sw) * 8 + (g & 1) * 4] = pkb;
            }

            short8 pa0a = *(const short8*)&Pw[w][ln][(g ^ sw) * 8];
            short8 pa1a = *(const short8*)&Pw[w][ln][((4 + g) ^ sw) * 8];
            short8 pa0b = *(const short8*)&Pw[w][16 + ln][(g ^ sw) * 8];
            short8 pa1b = *(const short8*)&Pw[w][16 + ln][((4 + g) ^ sw) * 8];

            // PV: each V fragment read feeds BOTH q-groups.
#pragma unroll
            for (int n = 0; n < 3; ++n) {
                short8 vb0 = *(const short8*)&Vs[buf][n * 16 + ln][(g ^ sw) * 8];
                short8 vb1 = *(const short8*)&Vs[buf][n * 16 + ln][((4 + g) ^ sw) * 8];
                floatx4 acc = (n == 0) ? oa0 : (n == 1) ? oa1 : oa2;
                acc = __builtin_amdgcn_mfma_f32_16x16x32_bf16(pa0a, vb0, acc, 0, 0, 0);
                acc = __builtin_amdgcn_mfma_f32_16x16x32_bf16(pa1a, vb1, acc, 0, 0, 0);
                if (n == 0) oa0 = acc; else if (n == 1) oa1 = acc; else oa2 = acc;
                floatx4 accb = (n == 0) ? ob0 : (n == 1) ? ob1 : ob2;
                accb = __builtin_amdgcn_mfma_f32_16x16x32_bf16(pa0b, vb0, accb, 0, 0, 0);
                accb = __builtin_amdgcn_mfma_f32_16x16x32_bf16(pa1b, vb1, accb, 0, 0, 0);
                if (n == 0) ob0 = accb; else if (n == 1) ob1 = accb; else ob2 = accb;
            }
            oa3 = __builtin_amdgcn_mfma_f32_16x16x32_bf16(pa0a, vone, oa3, 0, 0, 0);
            oa3 = __builtin_amdgcn_mfma_f32_16x16x32_bf16(pa1a, vone, oa3, 0, 0, 0);
            ob3 = __builtin_amdgcn_mfma_f32_16x16x32_bf16(pa0b, vone, ob3, 0, 0, 0);
            ob3 = __builtin_amdgcn_mfma_f32_16x16x32_bf16(pa1b, vone, ob3, 0, 0, 0);

            // stage prefetched tile kt+1 into the other buffer (its last
            // readers finished before the barrier that ended step kt-1).
            if (kt < qt) {
                unsigned short* kd = &Ks[buf ^ 1][0][0];
                unsigned short* vd = &Vs[buf ^ 1][0][0];
                *(short8*)(kd + offK0) = kr0;
                *(short8*)(kd + offK1) = kr1;
                *(short8*)(kd + offK2) = kr2;
                *(short8*)(vd + offV0) = vr0;
                *(short8*)(vd + offV1) = vr1;
                *(short8*)(vd + offV2) = vr2;
                if (tid < 64) kd[offM] = f2bf((1.0f - mr) * MBS);
            }
            HOT_BARRIER();   // single barrier per step; vmcnt NOT drained
        }

        if (ln == 0) {                               // per-wave region, no barrier
            *(floatx4*)&l_s[w][g * 4] = oa3;
            *(floatx4*)&l_s[w][16 + g * 4] = ob3;
        }
        floatx4 l4a = *(const floatx4*)&l_s[w][g * 4];
        floatx4 l4b = *(const floatx4*)&l_s[w][16 + g * 4];
#pragma unroll
        for (int r = 0; r < 4; ++r) {
            float invA = 1.0f / l4a[r];
            int t = q0 + w * 32 + g * 4 + r;
            unsigned short* dst = ctx + (size_t)(b * TT + t) * CC + h * HD;
            dst[ln] = f2bf(oa0[r] * invA);
            dst[16 + ln] = f2bf(oa1[r] * invA);
            dst[32 + ln] = f2bf(oa2[r] * invA);
            float invB = 1.0f / l4b[r];
            unsigned short* dstB = dst + (size_t)16 * CC;
            dstB[ln] = f2bf(ob0[r] * invB);
            dstB[16 + ln] = f2bf(ob1[r] * invB);
            dstB[32 + ln] = f2bf(ob2[r] * invB);
        }
    }
}

extern "C" void kernel_launch(void* const* d_in, const int* in_sizes, int n_in,
                              void* d_out, int out_size, void* d_ws, size_t ws_size,
                              hipStream_t stream) {
    const float* hs = (const float*)d_in[0];
    const float* amask = (const float*)d_in[1];
    const float* Wq = (const float*)d_in[2];
    const float* bq = (const float*)d_in[3];
    const float* Wk = (const float*)d_in[4];
    const float* bk = (const float*)d_in[5];
    const float* Wv = (const float*)d_in[6];
    const float* bv = (const float*)d_in[7];
    const float* Wo = (const float*)d_in[8];
    const float* bo = (const float*)d_in[9];

    const size_t NELEM = (size_t)BB * TT * CC;  // 6291456
    const size_t WELEM = (size_t)CC * CC;       // 589824
    unsigned short* hb  = (unsigned short*)d_ws;
    unsigned short* qbuf = hb + NELEM;
    unsigned short* kbuf = qbuf + NELEM;
    unsigned short* vtb = kbuf + NELEM;   // bf16 [B,H,D,T]
    unsigned short* ctxb = vtb + NELEM;
    unsigned short* wqb = ctxb + NELEM;   // wq/wk/wv contiguous = stacked [2304][768]
    unsigned short* wkb = wqb + WELEM;
    unsigned short* wvb = wkb + WELEM;
    unsigned short* wob = wvb + WELEM;
    float2* ropetab = (float2*)(wob + WELEM);  // [2048][24]

    cast_hs<<<NELEM / 1024, 256, 0, stream>>>(hs, hb);
    dim3 wgrid(WELEM / 1024, 4);
    cast_w4<<<wgrid, 256, 0, stream>>>(Wq, Wk, Wv, Wo, wqb, wkb, wvb, wob);
    rope_table<<<(TT * (HD / 2)) / 256, 256, 0, stream>>>(ropetab);

    gemm_mfma<1><<<18 * 64, 256, 0, stream>>>(hb, wqb, bq, bk, bv, qbuf, kbuf, vtb);

    int rope_total = BB * TT * NHD * 3;  // 8 pairs per thread
    rope_bf<<<rope_total / 256, 256, 0, stream>>>(qbuf, kbuf, ropetab);

    attn_kernel<<<1024, 128, 0, stream>>>(qbuf, kbuf, vtb, amask, ctxb);

    gemm_mfma<0><<<6 * 64, 256, 0, stream>>>(ctxb, wob, bo, nullptr, nullptr,
                                             (float*)d_out, nullptr, nullptr);
}

// Round 9
// 223.616 us; speedup vs baseline: 1.0914x; 1.0011x over previous
//
#include <hip/hip_runtime.h>
#include <hip/hip_bf16.h>
#include <math.h>

#define BB 4
#define TT 2048
#define CC 768
#define NHD 16
#define HD 48
#define NQT 32  // TT/64

typedef __hip_bfloat16 bf16;
typedef __attribute__((ext_vector_type(8))) short short8;
typedef __attribute__((ext_vector_type(4))) float floatx4;
typedef __attribute__((ext_vector_type(16))) float floatx16;
typedef __attribute__((ext_vector_type(2))) unsigned int uintx2;

__device__ __forceinline__ unsigned short f2bf(float x) {
    bf16 h = __float2bfloat16(x);
    return *(unsigned short*)&h;
}
__device__ __forceinline__ float bfu2f(unsigned short u) {
    return __uint_as_float(((unsigned)u) << 16);
}

// async global->LDS, 16B per lane; LDS dest = wave-uniform base + lane*16
__device__ __forceinline__ void gl_lds16(const void* g, void* s) {
    __builtin_amdgcn_global_load_lds((const __attribute__((address_space(1))) void*)g,
                                     (__attribute__((address_space(3))) void*)s, 16, 0, 0);
}

// single-instruction packed f32x2 -> bf16x2 (D.lo = cvt(S0), D.hi = cvt(S1))
__device__ __forceinline__ unsigned int cvtpk(float lo, float hi) {
    unsigned int r;
    asm("v_cvt_pk_bf16_f32 %0, %1, %2" : "=v"(r) : "v"(lo), "v"(hi));
    return r;
}

// Build PV A-fragment (16 k-positions, this lane's 8 = hi*8..hi*8+7) from the
// 8 P-values this lane owns for one 16-col k-block of the swapped-QK 32x32
// C layout (kcol = (r&3)+8*(r>>2)+4*hi). T12 recipe: one permlane32_swap of
// two cvt_pk dwords yields BOTH output words (self-half and partner-half).
__device__ __forceinline__ short8 build_pfrag(float p0, float p1, float p2, float p3,
                                              float p4, float p5, float p6, float p7) {
    unsigned int a = cvtpk(p0, p1);
    unsigned int b = cvtpk(p4, p5);
    unsigned int c = cvtpk(p2, p3);
    unsigned int d = cvtpk(p6, p7);
    uintx2 s1 = __builtin_amdgcn_permlane32_swap(a, b, false, false);
    uintx2 s2 = __builtin_amdgcn_permlane32_swap(c, d, false, false);
    union { unsigned int u[4]; short8 s; } r;
    r.u[0] = s1[0]; r.u[1] = s2[0]; r.u[2] = s1[1]; r.u[3] = s2[1];
    return r.s;
}

// hot-loop barrier: make LDS writes visible, do NOT drain vmcnt -- register
// global loads (K/V prefetch) stay in flight across the barrier.
#define HOT_BARRIER() asm volatile("s_waitcnt lgkmcnt(0)\n\ts_barrier" ::: "memory")

// ---------- fp32 -> bf16 casts ----------
__global__ __launch_bounds__(256) void cast_hs(const float* __restrict__ src,
                                               unsigned short* __restrict__ dst) {
    int i = (blockIdx.x * 256 + threadIdx.x) * 4;
    float4 v = *(const float4*)(src + i);
    ushort4 p;
    p.x = f2bf(v.x); p.y = f2bf(v.y); p.z = f2bf(v.z); p.w = f2bf(v.w);
    *(ushort4*)(dst + i) = p;
}

__global__ __launch_bounds__(256) void cast_w4(const float* __restrict__ s0, const float* __restrict__ s1,
                                               const float* __restrict__ s2, const float* __restrict__ s3,
                                               unsigned short* __restrict__ d0, unsigned short* __restrict__ d1,
                                               unsigned short* __restrict__ d2, unsigned short* __restrict__ d3) {
    const float* s; unsigned short* d;
    switch (blockIdx.y) {
        case 0: s = s0; d = d0; break;
        case 1: s = s1; d = d1; break;
        case 2: s = s2; d = d2; break;
        default: s = s3; d = d3; break;
    }
    int i = (blockIdx.x * 256 + threadIdx.x) * 4;
    float4 v = *(const float4*)(s + i);
    ushort4 p;
    p.x = f2bf(v.x); p.y = f2bf(v.y); p.z = f2bf(v.z); p.w = f2bf(v.w);
    *(ushort4*)(d + i) = p;
}

// ---------- RoPE sincos table: tab[t][p] = {cos, sin}, p in [0,24) ----------
__global__ __launch_bounds__(256) void rope_table(float2* __restrict__ tab) {
    int idx = blockIdx.x * 256 + threadIdx.x;  // over 2048*24
    int t = idx / 24, p = idx % 24;
    float inv_freq = powf(10000.0f, -((float)(2 * p) / (float)HD));
    float ang = (float)t * inv_freq;
    float sn, cs;
    sincosf(ang, &sn, &cs);
    tab[idx] = make_float2(cs, sn);
}

// ---------- bf16 MFMA NT-GEMM, BK=64, lds-direct staging with XOR-swizzle ----------
template <int MODE>
__global__ __launch_bounds__(256) void gemm_mfma(const unsigned short* __restrict__ A,
                                                 const unsigned short* __restrict__ Bw,
                                                 const float* __restrict__ b0p,
                                                 const float* __restrict__ b1p,
                                                 const float* __restrict__ b2p,
                                                 void* __restrict__ out0,
                                                 void* __restrict__ out1,
                                                 void* __restrict__ out2) {
    __shared__ __align__(16) unsigned short As[128][64];
    __shared__ __align__(16) unsigned short Bs[128][64];
    const int tid = threadIdx.x;
    const int w = tid >> 6, lane = tid & 63;
    const int quad = lane >> 4, ln = lane & 15;
    const int wr = w >> 1, wc = w & 1;

    const int NXB = (MODE == 1) ? 18 : 6;
    const int bx = blockIdx.x;
    const int xcd = bx & 7, slot = bx >> 3;
    const int n0 = (slot % NXB) * 128;
    const int m0 = ((slot / NXB) * 8 + xcd) * 128;

    const int srow = lane >> 3;
    const int ssw = ((lane & 7) ^ srow) * 8;
    const unsigned short* agp[4];
    const unsigned short* bgp[4];
    void* asl[4];
    void* bsl[4];
#pragma unroll
    for (int i = 0; i < 4; ++i) {
        const int R = i * 32 + w * 8;
        agp[i] = A + (size_t)(m0 + R + srow) * CC + ssw;
        bgp[i] = Bw + (size_t)(n0 + R + srow) * CC + ssw;
        asl[i] = &As[R][0];
        bsl[i] = &Bs[R][0];
    }

    floatx4 acc[4][4];
#pragma unroll
    for (int mi = 0; mi < 4; ++mi)
#pragma unroll
        for (int ni = 0; ni < 4; ++ni) acc[mi][ni] = (floatx4){0.f, 0.f, 0.f, 0.f};

    const int ps0 = (quad ^ (ln & 7)) * 8;

    for (int k0 = 0; k0 < CC; k0 += 64) {
        __syncthreads();
#pragma unroll
        for (int i = 0; i < 4; ++i) {
            gl_lds16(agp[i] + k0, asl[i]);
            gl_lds16(bgp[i] + k0, bsl[i]);
        }
        __syncthreads();
#pragma unroll
        for (int kh = 0; kh < 2; ++kh) {
            const int ps = ps0 ^ (kh * 32);
            short8 af[4], bfr[4];
#pragma unroll
            for (int mi = 0; mi < 4; ++mi)
                af[mi] = *(const short8*)&As[wr * 64 + mi * 16 + ln][ps];
#pragma unroll
            for (int ni = 0; ni < 4; ++ni)
                bfr[ni] = *(const short8*)&Bs[wc * 64 + ni * 16 + ln][ps];
#pragma unroll
            for (int mi = 0; mi < 4; ++mi)
#pragma unroll
                for (int ni = 0; ni < 4; ++ni)
                    acc[mi][ni] = __builtin_amdgcn_mfma_f32_16x16x32_bf16(af[mi], bfr[ni], acc[mi][ni], 0, 0, 0);
        }
    }

    if (MODE == 0) {
        float* outf = (float*)out0;
        float bv[4];
#pragma unroll
        for (int ni = 0; ni < 4; ++ni) bv[ni] = b0p[n0 + wc * 64 + ni * 16 + ln];
#pragma unroll
        for (int mi = 0; mi < 4; ++mi)
#pragma unroll
            for (int r = 0; r < 4; ++r) {
                size_t row = m0 + wr * 64 + mi * 16 + quad * 4 + r;
#pragma unroll
                for (int ni = 0; ni < 4; ++ni)
                    outf[row * CC + n0 + wc * 64 + ni * 16 + ln] = acc[mi][ni][r] + bv[ni];
            }
    } else {
        const int seg = n0 / CC;
        const int nl0 = n0 - seg * CC;
        const float* bp = (seg == 0) ? b0p : (seg == 1) ? b1p : b2p;
        float bv[4];
#pragma unroll
        for (int ni = 0; ni < 4; ++ni) bv[ni] = bp[nl0 + wc * 64 + ni * 16 + ln];

        if (seg < 2) {
            unsigned short* outb = (unsigned short*)(seg == 0 ? out0 : out1);
#pragma unroll
            for (int mi = 0; mi < 4; ++mi)
#pragma unroll
                for (int r = 0; r < 4; ++r) {
                    size_t row = m0 + wr * 64 + mi * 16 + quad * 4 + r;
#pragma unroll
                    for (int ni = 0; ni < 4; ++ni)
                        outb[row * CC + nl0 + wc * 64 + ni * 16 + ln] = f2bf(acc[mi][ni][r] + bv[ni]);
                }
        } else {
            unsigned short* outb = (unsigned short*)out2;
            const int b = m0 >> 11;
#pragma unroll
            for (int ni = 0; ni < 4; ++ni) {
                int col = nl0 + wc * 64 + ni * 16 + ln;
                int h = col / HD, d = col % HD;
                size_t base = (size_t)((b * NHD + h) * HD + d) * TT;
#pragma unroll
                for (int mi = 0; mi < 4; ++mi) {
                    int t = (m0 & 2047) + wr * 64 + mi * 16 + quad * 4;
                    ushort4 pk;
                    pk.x = f2bf(acc[mi][ni][0] + bv[ni]);
                    pk.y = f2bf(acc[mi][ni][1] + bv[ni]);
                    pk.z = f2bf(acc[mi][ni][2] + bv[ni]);
                    pk.w = f2bf(acc[mi][ni][3] + bv[ni]);
                    *(ushort4*)(outb + base + t) = pk;
                }
            }
        }
    }
}

// RoPE in-place via precomputed table, vectorized (8 pairs/thread).
__global__ __launch_bounds__(256) void rope_bf(unsigned short* __restrict__ q,
                                               unsigned short* __restrict__ k,
                                               const float2* __restrict__ tab) {
    int idx = blockIdx.x * blockDim.x + threadIdx.x;  // over B*T*H*3
    const int HALF = HD / 2;
    int p8 = idx % 3;
    int rest = idx / 3;
    int h = rest % NHD;
    int n = rest / NHD;        // b*T + t
    int t = n & (TT - 1);
    const float QSC = 0.14433756729740643f * 1.4426950408889634f;
    size_t base = (size_t)n * CC + h * HD + p8 * 8;
    const float2* tp = tab + t * HALF + p8 * 8;

    short8 q1 = *(const short8*)(q + base);
    short8 q2 = *(const short8*)(q + base + HALF);
    short8 k1 = *(const short8*)(k + base);
    short8 k2 = *(const short8*)(k + base + HALF);
    short8 r1, r2, s1, s2;
#pragma unroll
    for (int jj = 0; jj < 8; ++jj) {
        float2 cssn = tp[jj];
        float cs = cssn.x, sn = cssn.y;
        float a = bfu2f((unsigned short)q1[jj]), bb = bfu2f((unsigned short)q2[jj]);
        r1[jj] = (short)f2bf((a * cs - bb * sn) * QSC);
        r2[jj] = (short)f2bf((bb * cs + a * sn) * QSC);
        float c2 = bfu2f((unsigned short)k1[jj]), d2 = bfu2f((unsigned short)k2[jj]);
        s1[jj] = (short)f2bf(c2 * cs - d2 * sn);
        s2[jj] = (short)f2bf(d2 * cs + c2 * sn);
    }
    *(short8*)(q + base) = r1;
    *(short8*)(q + base + HALF) = r2;
    *(short8*)(k + base) = s1;
    *(short8*)(k + base + HALF) = s2;
}

// MFMA flash attention, exp2-domain, fixed softmax reference (m=0).
// Round-9: 32x32x16 MFMA with IN-REGISTER softmax (T12). Swapped QK^T
// (mfma(K,Q)) puts each lane's scores on its OWN q-row (C col=lane&31);
// P converts to the PV A-fragment with 16 cvt_pk + 8 permlane32_swap --
// the Pw LDS round-trip (12 DS ops + 2 lgkm chain segments per step that
// R7/R8 isolated as the serial bottleneck) is GONE. V stays in swizzled
// LDS (R7: global-V scatter hurt); its B-frags are read before the softmax
// VALU so latency hides under it. l via ones-row at V d=48; mask column
// trick unchanged (K col48 x Q"d48"=1.0, 4th QK MFMA). Keeps R8's
// double-buffer single-barrier loop, balanced pair grid 1024, XCD pinning.
__global__ __launch_bounds__(128, 2) void attn_kernel(const unsigned short* __restrict__ qb,
                                                      const unsigned short* __restrict__ kb,
                                                      const unsigned short* __restrict__ vt,
                                                      const float* __restrict__ amask,
                                                      unsigned short* __restrict__ ctx) {
    const int bx = blockIdx.x;
    const int xcd = bx & 7;
    const int s = bx >> 3;              // [0,128)
    const int bh_l = s & 7;             // 8 (b,h) per XCD
    const int pairidx = s >> 3;         // [0,16)
    const int j = (bh_l << 3) | xcd;    // (b,h) pinned per XCD
    const int b = j >> 4, h = j & 15;
    const int tid = threadIdx.x;        // [0,128)
    const int w = tid >> 6, lane = tid & 63;
    const int l5 = lane & 31, hi = lane >> 5;

    // Ks rows = kcol 0..63, cols = d (48 real + mask col 48 + zero pad).
    // Vs rows = d 0..63 (48 real + ones row 48 + zero pad), cols = t (kcol).
    __shared__ __align__(16) unsigned short Ks[2][64][64];
    __shared__ __align__(16) unsigned short Vs[2][64][64];
    __shared__ __align__(16) float l_s[2][2][16];

    const short8 z8 = {0, 0, 0, 0, 0, 0, 0, 0};
    const short8 ones8 = {0x3F80, 0x3F80, 0x3F80, 0x3F80, 0x3F80, 0x3F80, 0x3F80, 0x3F80};

    {   // Ks pad units 6,7 (swizzled) zero, both buffers; mask slot rewritten/step
        int rr = tid & 63, half = tid >> 6;
        *(short8*)&Ks[0][rr][((6 + half) ^ (rr & 7)) * 8] = z8;
        *(short8*)&Ks[1][rr][((6 + half) ^ (rr & 7)) * 8] = z8;
        // Vs rows 48..63: row 48 = ones (l accumulator), 49..63 = zero.
        // Whole-row constant => swizzle-free writes are safe.
        int vr = 48 + (tid >> 3), vu = tid & 7;
        short8 pv = (vr == 48) ? ones8 : z8;
        *(short8*)&Vs[0][vr][vu * 8] = pv;
        *(short8*)&Vs[1][vr][vu * 8] = pv;
    }

    // staging: 3 K-units (64x6) and 3 V-units (48x8) per thread
    const int u0 = tid, u1 = tid + 128, u2 = tid + 256;
    const int rK0 = u0 / 6, sK0 = u0 % 6;
    const int rK1 = u1 / 6, sK1 = u1 % 6;
    const int rK2 = u2 / 6, sK2 = u2 % 6;
    const int rV0 = u0 >> 3, sV0 = u0 & 7;
    const int rV1 = u1 >> 3, sV1 = u1 & 7;
    const int rV2 = u2 >> 3, sV2 = u2 & 7;
    const int offK0 = rK0 * 64 + (sK0 ^ (rK0 & 7)) * 8;
    const int offK1 = rK1 * 64 + (sK1 ^ (rK1 & 7)) * 8;
    const int offK2 = rK2 * 64 + (sK2 ^ (rK2 & 7)) * 8;
    const int offV0 = rV0 * 64 + (sV0 ^ (rV0 & 7)) * 8;
    const int offV1 = rV1 * 64 + (sV1 ^ (rV1 & 7)) * 8;
    const int offV2 = rV2 * 64 + (sV2 ^ (rV2 & 7)) * 8;
    const int offM = (tid & 63) * 64 + (6 ^ (tid & 7)) * 8;  // mask slot, row=tid(<64)

    const unsigned short* kbase0 = kb + (size_t)(b * TT + rK0) * CC + h * HD + sK0 * 8;
    const unsigned short* kbase1 = kb + (size_t)(b * TT + rK1) * CC + h * HD + sK1 * 8;
    const unsigned short* kbase2 = kb + (size_t)(b * TT + rK2) * CC + h * HD + sK2 * 8;
    const unsigned short* vbase0 = vt + ((size_t)((b * NHD + h) * HD) + rV0) * TT + sV0 * 8;
    const unsigned short* vbase1 = vt + ((size_t)((b * NHD + h) * HD) + rV1) * TT + sV1 * 8;
    const unsigned short* vbase2 = vt + ((size_t)((b * NHD + h) * HD) + rV2) * TT + sV2 * 8;
    const float* mbase = amask + b * TT + (tid & 63);
    const float MBS = -10000.0f * 1.4426950408889634f;
    const int swz = l5 & 7;   // row-derived XOR for frag reads (row&7 == l5&7)

    for (int rep = 0; rep < 2; ++rep) {
        const int qt = rep ? (NQT - 1 - pairidx) : pairidx;   // steps = qt+1
        const int q0 = qt * 64;

        // Q fragments: lane holds Q[qrow = w*32+l5][d = d0 + hi*8 + j].
        // qf[3] is the mask-column constant: d=48 -> 1.0 (hi==0, j==0).
        const unsigned short* qr = qb + (size_t)(b * TT + q0 + w * 32 + l5) * CC + h * HD + hi * 8;
        short8 qf[4];
        qf[0] = *(const short8*)(qr);
        qf[1] = *(const short8*)(qr + 16);
        qf[2] = *(const short8*)(qr + 32);
        qf[3] = z8;
        if (hi == 0) qf[3][0] = (short)0x3F80;

        const unsigned short* kp0 = kbase0;
        const unsigned short* kp1 = kbase1;
        const unsigned short* kp2 = kbase2;
        const unsigned short* vp0 = vbase0;
        const unsigned short* vp1 = vbase1;
        const unsigned short* vp2 = vbase2;
        const float* mp = mbase;

        // prologue: tile 0 -> regs -> buf0
        short8 kr0 = *(const short8*)kp0;
        short8 kr1 = *(const short8*)kp1;
        short8 kr2 = *(const short8*)kp2;
        short8 vr0 = *(const short8*)vp0;
        short8 vr1 = *(const short8*)vp1;
        short8 vr2 = *(const short8*)vp2;
        float mr = (tid < 64) ? *mp : 1.0f;

        HOT_BARRIER();   // all waves done reading buffers (prev rep)
        {
            unsigned short* kd = &Ks[0][0][0];
            unsigned short* vd = &Vs[0][0][0];
            *(short8*)(kd + offK0) = kr0;
            *(short8*)(kd + offK1) = kr1;
            *(short8*)(kd + offK2) = kr2;
            *(short8*)(vd + offV0) = vr0;
            *(short8*)(vd + offV1) = vr1;
            *(short8*)(vd + offV2) = vr2;
            if (tid < 64) kd[offM] = f2bf((1.0f - mr) * MBS);
        }
        HOT_BARRIER();   // buf0 visible

        floatx16 oA = (floatx16){0.f, 0.f, 0.f, 0.f, 0.f, 0.f, 0.f, 0.f,
                                 0.f, 0.f, 0.f, 0.f, 0.f, 0.f, 0.f, 0.f};
        floatx16 oB = oA;

        for (int kt = 0; kt <= qt; ++kt) {
            const int buf = kt & 1;
            const unsigned short* ksb = &Ks[buf][0][0];
            const unsigned short* vsb = &Vs[buf][0][0];

            if (kt < qt) {   // issue global prefetch for tile kt+1 (regs)
                kp0 += (size_t)64 * CC; kr0 = *(const short8*)kp0;
                kp1 += (size_t)64 * CC; kr1 = *(const short8*)kp1;
                kp2 += (size_t)64 * CC; kr2 = *(const short8*)kp2;
                vp0 += 64; vr0 = *(const short8*)vp0;
                vp1 += 64; vr1 = *(const short8*)vp1;
                vp2 += 64; vr2 = *(const short8*)vp2;
                if (tid < 64) { mp += 64; mr = *mp; }
            }

            // QK^T (swapped): A = K[kcol][d] (row=l5(+32), k-slice by hi),
            // B = Q. Two 32-kcol tiles; 4 d-slices each (incl mask col).
            floatx16 sc0 = (floatx16){0.f, 0.f, 0.f, 0.f, 0.f, 0.f, 0.f, 0.f,
                                      0.f, 0.f, 0.f, 0.f, 0.f, 0.f, 0.f, 0.f};
            floatx16 sc1 = sc0;
#pragma unroll
            for (int i = 0; i < 4; ++i) {
                short8 kf0 = *(const short8*)(ksb + (size_t)l5 * 64 + ((2 * i + hi) ^ swz) * 8);
                short8 kf1 = *(const short8*)(ksb + (size_t)(32 + l5) * 64 + ((2 * i + hi) ^ swz) * 8);
                sc0 = __builtin_amdgcn_mfma_f32_32x32x16_bf16(kf0, qf[i], sc0, 0, 0, 0);
                sc1 = __builtin_amdgcn_mfma_f32_32x32x16_bf16(kf1, qf[i], sc1, 0, 0, 0);
            }

            // V B-frags issued BEFORE the softmax VALU block (latency hides).
            // B[k=kcol][n=d]: read Vs[nt*32+l5][kb*16 + hi*8 ..+7].
            short8 vA[4], vB[4];
#pragma unroll
            for (int kb2 = 0; kb2 < 4; ++kb2) {
                vA[kb2] = *(const short8*)(vsb + (size_t)l5 * 64 + ((kb2 * 2 + hi) ^ swz) * 8);
                vB[kb2] = *(const short8*)(vsb + (size_t)(32 + l5) * 64 + ((kb2 * 2 + hi) ^ swz) * 8);
            }

            // softmax (exp2-domain), fully in-register
            float p0[16], p1[16];
#pragma unroll
            for (int r = 0; r < 16; ++r) {
                p0[r] = __builtin_amdgcn_exp2f(sc0[r]);
                p1[r] = __builtin_amdgcn_exp2f(sc1[r]);
            }
            if (kt == qt) {   // uniform branch: only the diagonal step pays
                const int qrl = w * 32 + l5;
#pragma unroll
                for (int r = 0; r < 16; ++r) {
                    int cr = (r & 3) + 8 * (r >> 2) + 4 * hi;
                    if (cr > qrl) p0[r] = 0.f;
                    if (32 + cr > qrl) p1[r] = 0.f;
                }
            }

            // P -> PV A-frags: 16 cvt_pk + 8 permlane32_swap, no LDS.
            short8 pa0 = build_pfrag(p0[0], p0[1], p0[2], p0[3], p0[4], p0[5], p0[6], p0[7]);
            short8 pa1 = build_pfrag(p0[8], p0[9], p0[10], p0[11], p0[12], p0[13], p0[14], p0[15]);
            short8 pa2 = build_pfrag(p1[0], p1[1], p1[2], p1[3], p1[4], p1[5], p1[6], p1[7]);
            short8 pa3 = build_pfrag(p1[8], p1[9], p1[10], p1[11], p1[12], p1[13], p1[14], p1[15]);

            // PV: D[qrow][d]; oA = d 0..31, oB = d 32..63 (col 48 = l).
            oA = __builtin_amdgcn_mfma_f32_32x32x16_bf16(pa0, vA[0], oA, 0, 0, 0);
            oB = __builtin_amdgcn_mfma_f32_32x32x16_bf16(pa0, vB[0], oB, 0, 0, 0);
            oA = __builtin_amdgcn_mfma_f32_32x32x16_bf16(pa1, vA[1], oA, 0, 0, 0);
            oB = __builtin_amdgcn_mfma_f32_32x32x16_bf16(pa1, vB[1], oB, 0, 0, 0);
            oA = __builtin_amdgcn_mfma_f32_32x32x16_bf16(pa2, vA[2], oA, 0, 0, 0);
            oB = __builtin_amdgcn_mfma_f32_32x32x16_bf16(pa2, vB[2], oB, 0, 0, 0);
            oA = __builtin_amdgcn_mfma_f32_32x32x16_bf16(pa3, vA[3], oA, 0, 0, 0);
            oB = __builtin_amdgcn_mfma_f32_32x32x16_bf16(pa3, vB[3], oB, 0, 0, 0);

            // stage prefetched tile kt+1 into the other buffer
            if (kt < qt) {
                unsigned short* kd = &Ks[buf ^ 1][0][0];
                unsigned short* vd = &Vs[buf ^ 1][0][0];
                *(short8*)(kd + offK0) = kr0;
                *(short8*)(kd + offK1) = kr1;
                *(short8*)(kd + offK2) = kr2;
                *(short8*)(vd + offV0) = vr0;
                *(short8*)(vd + offV1) = vr1;
                *(short8*)(vd + offV2) = vr2;
                if (tid < 64) kd[offM] = f2bf((1.0f - mr) * MBS);
            }
            HOT_BARRIER();   // single barrier per step; vmcnt NOT drained
        }

        // l lives in oB at n-col 16 (ones-row at V d=48): lane (hi, l5==16)
        // holds l for the same 16 q-rows as every lane in its half-wave.
        if (l5 == 16) {
#pragma unroll
            for (int r = 0; r < 16; ++r) l_s[w][hi][r] = oB[r];
        }
        asm volatile("s_waitcnt lgkmcnt(0)" ::: "memory");  // same-wave visibility

#pragma unroll
        for (int r = 0; r < 16; ++r) {
            float inv_l = 1.0f / l_s[w][hi][r];
            int t = q0 + w * 32 + ((r & 3) + 8 * (r >> 2) + 4 * hi);
            unsigned short* dst = ctx + (size_t)(b * TT + t) * CC + h * HD;
            dst[l5] = f2bf(oA[r] * inv_l);
            if (l5 < 16) dst[32 + l5] = f2bf(oB[r] * inv_l);
        }
    }
}

extern "C" void kernel_launch(void* const* d_in, const int* in_sizes, int n_in,
                              void* d_out, int out_size, void* d_ws, size_t ws_size,
                              hipStream_t stream) {
    const float* hs = (const float*)d_in[0];
    const float* amask = (const float*)d_in[1];
    const float* Wq = (const float*)d_in[2];
    const float* bq = (const float*)d_in[3];
    const float* Wk = (const float*)d_in[4];
    const float* bk = (const float*)d_in[5];
    const float* Wv = (const float*)d_in[6];
    const float* bv = (const float*)d_in[7];
    const float* Wo = (const float*)d_in[8];
    const float* bo = (const float*)d_in[9];

    const size_t NELEM = (size_t)BB * TT * CC;  // 6291456
    const size_t WELEM = (size_t)CC * CC;       // 589824
    unsigned short* hb  = (unsigned short*)d_ws;
    unsigned short* qbuf = hb + NELEM;
    unsigned short* kbuf = qbuf + NELEM;
    unsigned short* vtb = kbuf + NELEM;   // bf16 [B,H,D,T]
    unsigned short* ctxb = vtb + NELEM;
    unsigned short* wqb = ctxb + NELEM;   // wq/wk/wv contiguous = stacked [2304][768]
    unsigned short* wkb = wqb + WELEM;
    unsigned short* wvb = wkb + WELEM;
    unsigned short* wob = wvb + WELEM;
    float2* ropetab = (float2*)(wob + WELEM);  // [2048][24]

    cast_hs<<<NELEM / 1024, 256, 0, stream>>>(hs, hb);
    dim3 wgrid(WELEM / 1024, 4);
    cast_w4<<<wgrid, 256, 0, stream>>>(Wq, Wk, Wv, Wo, wqb, wkb, wvb, wob);
    rope_table<<<(TT * (HD / 2)) / 256, 256, 0, stream>>>(ropetab);

    gemm_mfma<1><<<18 * 64, 256, 0, stream>>>(hb, wqb, bq, bk, bv, qbuf, kbuf, vtb);

    int rope_total = BB * TT * NHD * 3;  // 8 pairs per thread
    rope_bf<<<rope_total / 256, 256, 0, stream>>>(qbuf, kbuf, ropetab);

    attn_kernel<<<1024, 128, 0, stream>>>(qbuf, kbuf, vtb, amask, ctxb);

    gemm_mfma<0><<<6 * 64, 256, 0, stream>>>(ctxb, wob, bo, nullptr, nullptr,
                                             (float*)d_out, nullptr, nullptr);
}

// Round 11
// 221.228 us; speedup vs baseline: 1.1032x; 1.0108x over previous
//
#include <hip/hip_runtime.h>
#include <hip/hip_bf16.h>
#include <math.h>

#define BB 4
#define TT 2048
#define CC 768
#define NHD 16
#define HD 48
#define NQT2 16  // TT/128

typedef __hip_bfloat16 bf16;
typedef __attribute__((ext_vector_type(8))) short short8;
typedef __attribute__((ext_vector_type(4))) float floatx4;

__device__ __forceinline__ unsigned short f2bf(float x) {
    bf16 h = __float2bfloat16(x);
    return *(unsigned short*)&h;
}
__device__ __forceinline__ float bfu2f(unsigned short u) {
    return __uint_as_float(((unsigned)u) << 16);
}

// async global->LDS, 16B per lane; LDS dest = wave-uniform base + lane*16
__device__ __forceinline__ void gl_lds16(const void* g, void* s) {
    __builtin_amdgcn_global_load_lds((const __attribute__((address_space(1))) void*)g,
                                     (__attribute__((address_space(3))) void*)s, 16, 0, 0);
}

// pack two fp32 -> packed bf16 pair (round-half-up; inputs are probabilities >= 0)
__device__ __forceinline__ unsigned int pk_bf2(float a, float b) {
    unsigned int ua = __float_as_uint(a) + 0x8000u;
    unsigned int ub = __float_as_uint(b) + 0x8000u;
    return __builtin_amdgcn_perm(ub, ua, 0x07060302);
}

// hot-loop barrier: make LDS writes visible, do NOT drain vmcnt -- register
// global loads (K/V prefetch) stay in flight across the barrier.
#define HOT_BARRIER() asm volatile("s_waitcnt lgkmcnt(0)\n\ts_barrier" ::: "memory")

// ---------- fp32 -> bf16 casts ----------
__global__ __launch_bounds__(256) void cast_hs(const float* __restrict__ src,
                                               unsigned short* __restrict__ dst) {
    int i = (blockIdx.x * 256 + threadIdx.x) * 4;
    float4 v = *(const float4*)(src + i);
    ushort4 p;
    p.x = f2bf(v.x); p.y = f2bf(v.y); p.z = f2bf(v.z); p.w = f2bf(v.w);
    *(ushort4*)(dst + i) = p;
}

__global__ __launch_bounds__(256) void cast_w4(const float* __restrict__ s0, const float* __restrict__ s1,
                                               const float* __restrict__ s2, const float* __restrict__ s3,
                                               unsigned short* __restrict__ d0, unsigned short* __restrict__ d1,
                                               unsigned short* __restrict__ d2, unsigned short* __restrict__ d3) {
    const float* s; unsigned short* d;
    switch (blockIdx.y) {
        case 0: s = s0; d = d0; break;
        case 1: s = s1; d = d1; break;
        case 2: s = s2; d = d2; break;
        default: s = s3; d = d3; break;
    }
    int i = (blockIdx.x * 256 + threadIdx.x) * 4;
    float4 v = *(const float4*)(s + i);
    ushort4 p;
    p.x = f2bf(v.x); p.y = f2bf(v.y); p.z = f2bf(v.z); p.w = f2bf(v.w);
    *(ushort4*)(d + i) = p;
}

// ---------- RoPE sincos table: tab[t][p] = {cos, sin}, p in [0,24) ----------
__global__ __launch_bounds__(256) void rope_table(float2* __restrict__ tab) {
    int idx = blockIdx.x * 256 + threadIdx.x;  // over 2048*24
    int t = idx / 24, p = idx % 24;
    float inv_freq = powf(10000.0f, -((float)(2 * p) / (float)HD));
    float ang = (float)t * inv_freq;
    float sn, cs;
    sincosf(ang, &sn, &cs);
    tab[idx] = make_float2(cs, sn);
}

// ---------- bf16 MFMA NT-GEMM, BK=64, lds-direct staging with XOR-swizzle ----------
template <int MODE>
__global__ __launch_bounds__(256) void gemm_mfma(const unsigned short* __restrict__ A,
                                                 const unsigned short* __restrict__ Bw,
                                                 const float* __restrict__ b0p,
                                                 const float* __restrict__ b1p,
                                                 const float* __restrict__ b2p,
                                                 void* __restrict__ out0,
                                                 void* __restrict__ out1,
                                                 void* __restrict__ out2) {
    __shared__ __align__(16) unsigned short As[128][64];
    __shared__ __align__(16) unsigned short Bs[128][64];
    const int tid = threadIdx.x;
    const int w = tid >> 6, lane = tid & 63;
    const int quad = lane >> 4, ln = lane & 15;
    const int wr = w >> 1, wc = w & 1;

    const int NXB = (MODE == 1) ? 18 : 6;
    const int bx = blockIdx.x;
    const int xcd = bx & 7, slot = bx >> 3;
    const int n0 = (slot % NXB) * 128;
    const int m0 = ((slot / NXB) * 8 + xcd) * 128;

    const int srow = lane >> 3;
    const int ssw = ((lane & 7) ^ srow) * 8;
    const unsigned short* agp[4];
    const unsigned short* bgp[4];
    void* asl[4];
    void* bsl[4];
#pragma unroll
    for (int i = 0; i < 4; ++i) {
        const int R = i * 32 + w * 8;
        agp[i] = A + (size_t)(m0 + R + srow) * CC + ssw;
        bgp[i] = Bw + (size_t)(n0 + R + srow) * CC + ssw;
        asl[i] = &As[R][0];
        bsl[i] = &Bs[R][0];
    }

    floatx4 acc[4][4];
#pragma unroll
    for (int mi = 0; mi < 4; ++mi)
#pragma unroll
        for (int ni = 0; ni < 4; ++ni) acc[mi][ni] = (floatx4){0.f, 0.f, 0.f, 0.f};

    const int ps0 = (quad ^ (ln & 7)) * 8;

    for (int k0 = 0; k0 < CC; k0 += 64) {
        __syncthreads();
#pragma unroll
        for (int i = 0; i < 4; ++i) {
            gl_lds16(agp[i] + k0, asl[i]);
            gl_lds16(bgp[i] + k0, bsl[i]);
        }
        __syncthreads();
#pragma unroll
        for (int kh = 0; kh < 2; ++kh) {
            const int ps = ps0 ^ (kh * 32);
            short8 af[4], bfr[4];
#pragma unroll
            for (int mi = 0; mi < 4; ++mi)
                af[mi] = *(const short8*)&As[wr * 64 + mi * 16 + ln][ps];
#pragma unroll
            for (int ni = 0; ni < 4; ++ni)
                bfr[ni] = *(const short8*)&Bs[wc * 64 + ni * 16 + ln][ps];
#pragma unroll
            for (int mi = 0; mi < 4; ++mi)
#pragma unroll
                for (int ni = 0; ni < 4; ++ni)
                    acc[mi][ni] = __builtin_amdgcn_mfma_f32_16x16x32_bf16(af[mi], bfr[ni], acc[mi][ni], 0, 0, 0);
        }
    }

    if (MODE == 0) {
        float* outf = (float*)out0;
        float bv[4];
#pragma unroll
        for (int ni = 0; ni < 4; ++ni) bv[ni] = b0p[n0 + wc * 64 + ni * 16 + ln];
#pragma unroll
        for (int mi = 0; mi < 4; ++mi)
#pragma unroll
            for (int r = 0; r < 4; ++r) {
                size_t row = m0 + wr * 64 + mi * 16 + quad * 4 + r;
#pragma unroll
                for (int ni = 0; ni < 4; ++ni)
                    outf[row * CC + n0 + wc * 64 + ni * 16 + ln] = acc[mi][ni][r] + bv[ni];
            }
    } else {
        const int seg = n0 / CC;
        const int nl0 = n0 - seg * CC;
        const float* bp = (seg == 0) ? b0p : (seg == 1) ? b1p : b2p;
        float bv[4];
#pragma unroll
        for (int ni = 0; ni < 4; ++ni) bv[ni] = bp[nl0 + wc * 64 + ni * 16 + ln];

        if (seg < 2) {
            unsigned short* outb = (unsigned short*)(seg == 0 ? out0 : out1);
#pragma unroll
            for (int mi = 0; mi < 4; ++mi)
#pragma unroll
                for (int r = 0; r < 4; ++r) {
                    size_t row = m0 + wr * 64 + mi * 16 + quad * 4 + r;
#pragma unroll
                    for (int ni = 0; ni < 4; ++ni)
                        outb[row * CC + nl0 + wc * 64 + ni * 16 + ln] = f2bf(acc[mi][ni][r] + bv[ni]);
                }
        } else {
            unsigned short* outb = (unsigned short*)out2;
            const int b = m0 >> 11;
#pragma unroll
            for (int ni = 0; ni < 4; ++ni) {
                int col = nl0 + wc * 64 + ni * 16 + ln;
                int h = col / HD, d = col % HD;
                size_t base = (size_t)((b * NHD + h) * HD + d) * TT;
#pragma unroll
                for (int mi = 0; mi < 4; ++mi) {
                    int t = (m0 & 2047) + wr * 64 + mi * 16 + quad * 4;
                    ushort4 pk;
                    pk.x = f2bf(acc[mi][ni][0] + bv[ni]);
                    pk.y = f2bf(acc[mi][ni][1] + bv[ni]);
                    pk.z = f2bf(acc[mi][ni][2] + bv[ni]);
                    pk.w = f2bf(acc[mi][ni][3] + bv[ni]);
                    *(ushort4*)(outb + base + t) = pk;
                }
            }
        }
    }
}

// RoPE in-place via precomputed table, vectorized (8 pairs/thread).
__global__ __launch_bounds__(256) void rope_bf(unsigned short* __restrict__ q,
                                               unsigned short* __restrict__ k,
                                               const float2* __restrict__ tab) {
    int idx = blockIdx.x * blockDim.x + threadIdx.x;  // over B*T*H*3
    const int HALF = HD / 2;
    int p8 = idx % 3;
    int rest = idx / 3;
    int h = rest % NHD;
    int n = rest / NHD;        // b*T + t
    int t = n & (TT - 1);
    const float QSC = 0.14433756729740643f * 1.4426950408889634f;
    size_t base = (size_t)n * CC + h * HD + p8 * 8;
    const float2* tp = tab + t * HALF + p8 * 8;

    short8 q1 = *(const short8*)(q + base);
    short8 q2 = *(const short8*)(q + base + HALF);
    short8 k1 = *(const short8*)(k + base);
    short8 k2 = *(const short8*)(k + base + HALF);
    short8 r1, r2, s1, s2;
#pragma unroll
    for (int jj = 0; jj < 8; ++jj) {
        float2 cssn = tp[jj];
        float cs = cssn.x, sn = cssn.y;
        float a = bfu2f((unsigned short)q1[jj]), bb = bfu2f((unsigned short)q2[jj]);
        r1[jj] = (short)f2bf((a * cs - bb * sn) * QSC);
        r2[jj] = (short)f2bf((bb * cs + a * sn) * QSC);
        float c2 = bfu2f((unsigned short)k1[jj]), d2 = bfu2f((unsigned short)k2[jj]);
        s1[jj] = (short)f2bf(c2 * cs - d2 * sn);
        s2[jj] = (short)f2bf(d2 * cs + c2 * sn);
    }
    *(short8*)(q + base) = r1;
    *(short8*)(q + base + HALF) = r2;
    *(short8*)(k + base) = s1;
    *(short8*)(k + base + HALF) = s2;
}

// MFMA flash attention, exp2-domain, fixed softmax reference (m=0).
// Round-11 = REVERT to the harness-verified session best (round 4, 54.5us
// attn / 221.25us total): 128 q-rows per block (two 64-row groups a/b per
// wave: each wave owns 32 q-rows), so every K/V fragment read from LDS feeds
// TWO MFMAs. K and V live in LDS (XOR-swizzled, [64] cols); both barriers
// are lgkm-only so the K/V register prefetch stays in flight. Q direct from
// global. Grid 512 = 64 (b,h) x 8 pairs; pair schedule (qt, 15-qt) = exactly
// 34 k-steps per block; XCD-pinned -> exactly 2 blocks/CU, zero tail.
// launch_bounds(256,2): 256-VGPR cap eliminates the spill failure mode.
// Session verdict: R5-R9 structural attacks (V-out-of-LDS, in-register
// softmax, single-barrier dbuf on 2-wave bases) landed 57-60us; R10's
// 4-wave single-barrier graft FAILED correctness. This exact kernel is the
// measured optimum of the explored space.
__global__ __launch_bounds__(256, 2) void attn_kernel(const unsigned short* __restrict__ qb,
                                                      const unsigned short* __restrict__ kb,
                                                      const unsigned short* __restrict__ vt,
                                                      const float* __restrict__ amask,
                                                      unsigned short* __restrict__ ctx) {
    const int bx = blockIdx.x;
    const int xcd = bx & 7;
    const int rem = bx >> 3;                // [0,64)
    const int pair = rem & 7;
    const int j = ((rem >> 3) << 3) | xcd;  // (b,h) group, grouped per XCD
    const int b = j >> 4, h = j & 15;
    const int tid = threadIdx.x;
    const int w = tid >> 6, lane = tid & 63;
    const int g = lane >> 4, ln = lane & 15;
    const int sw = ln & 7;

    __shared__ __align__(16) unsigned short Ks[64][64];
    __shared__ __align__(16) unsigned short Vs[48][64];
    __shared__ __align__(16) unsigned short Pw[4][32][64];
    __shared__ __align__(16) float l_s[4][32];

    const short8 z8 = {0, 0, 0, 0, 0, 0, 0, 0};
    const short8 ones8 = {0x3F80, 0x3F80, 0x3F80, 0x3F80, 0x3F80, 0x3F80, 0x3F80, 0x3F80};

    // zero Ks pad units 6,7 (XOR-swizzled) once; unit-6 elem 0 = mask slot
    // (rewritten each step), elems 1..7 and unit 7 stay 0.
    if (tid < 128) {
        int rr = tid >> 1, half = tid & 1;
        *(short8*)&Ks[rr][((6 + half) ^ (rr & 7)) * 8] = z8;
    }

    // K stage: 64 rows x 6 units (48 cols). V stage: 48 rows x 8 units (64 cols).
    const int ck1 = tid + 256;
    const int rK0 = tid / 6, sK0 = tid % 6;
    const int rK1 = ck1 / 6, sK1 = ck1 % 6;
    const int swK0 = (sK0 ^ (rK0 & 7)) * 8;
    const int swK1 = (sK1 ^ (rK1 & 7)) * 8;
    const int rV0 = tid >> 3, sV0 = tid & 7;   // rows 0..31
    const int rV1 = rV0 + 32;                  // tid<128: rows 32..47
    const int swV0 = (sV0 ^ (rV0 & 7)) * 8;
    const int swV1 = (sV0 ^ (rV1 & 7)) * 8;

    const unsigned short* kbase0 = kb + (size_t)(b * TT + rK0) * CC + h * HD + sK0 * 8;
    const unsigned short* kbase1 = kb + (size_t)(b * TT + rK1) * CC + h * HD + sK1 * 8;
    const unsigned short* vbase0 = vt + ((size_t)((b * NHD + h) * HD) + rV0) * TT + sV0 * 8;
    const unsigned short* vbase1 = vbase0 + (size_t)32 * TT;
    const float* mbase = amask + b * TT + (tid & 63);
    const float MBS = -10000.0f * 1.4426950408889634f;
    const int mcol = (6 ^ (lane & 7)) * 8;     // swizzled mask slot (row = lane)
    const short8 vone = (ln == 0) ? ones8 : z8;  // ones-column B-frag (l accumulator)

    for (int rep = 0; rep < 2; ++rep) {
        const int qt = rep ? (NQT2 - 1 - pair) : pair;
        const int q0 = qt * 128;
        const int last = 2 * qt + 1;

        // Q fragments straight from global, two row-groups per wave.
        const unsigned short* qrA = qb + (size_t)(b * TT + q0 + w * 16 + ln) * CC + h * HD;
        const unsigned short* qrB = qrA + (size_t)64 * CC;
        short8 aq0a = *(const short8*)(qrA + g * 8);
        short8 aq0b = *(const short8*)(qrB + g * 8);
        short8 aq1a, aq1b;
        if (g < 2) {
            aq1a = *(const short8*)(qrA + 32 + g * 8);
            aq1b = *(const short8*)(qrB + 32 + g * 8);
        } else {
            aq1a = z8; aq1b = z8;
            if (g == 2) { aq1a[0] = (short)0x3F80; aq1b[0] = (short)0x3F80; }
        }

        const unsigned short* kp0 = kbase0;
        const unsigned short* kp1 = kbase1;
        const unsigned short* vp0 = vbase0;
        const unsigned short* vp1 = vbase1;
        const float* mp = mbase;

        short8 kr0, kr1, vr0, vr1;
        float mr = 1.0f;
        kr0 = *(const short8*)kp0;
        vr0 = *(const short8*)vp0;
        if (tid < 128) { kr1 = *(const short8*)kp1; vr1 = *(const short8*)vp1; }
        if (tid < 64) mr = *mp;

        const int qlA = q0 + w * 16 + ln;
        const int qlB = qlA + 64;
        floatx4 oa0 = {0.f, 0.f, 0.f, 0.f}, oa1 = oa0, oa2 = oa0, oa3 = oa0;
        floatx4 ob0 = oa0, ob1 = oa0, ob2 = oa0, ob3 = oa0;

        for (int kt = 0; kt <= last; ++kt) {
            HOT_BARRIER();   // prior step's LDS reads complete
            *(short8*)&Ks[rK0][swK0] = kr0;
            *(short8*)&Vs[rV0][swV0] = vr0;
            if (tid < 128) {
                *(short8*)&Ks[rK1][swK1] = kr1;
                *(short8*)&Vs[rV1][swV1] = vr1;
            }
            if (tid < 64) Ks[lane][mcol] = f2bf((1.0f - mr) * MBS);
            HOT_BARRIER();   // writes visible; vmcnt NOT drained

            if (kt < last) {
                kp0 += (size_t)64 * CC; kr0 = *(const short8*)kp0;
                vp0 += 64;              vr0 = *(const short8*)vp0;
                if (tid < 128) {
                    kp1 += (size_t)64 * CC; kr1 = *(const short8*)kp1;
                    vp1 += 64;              vr1 = *(const short8*)vp1;
                }
                if (tid < 64) { mp += 64; mr = *mp; }
            }

            const int k0 = kt * 64;
            const bool a_act = (kt <= 2 * qt);
            const bool diagA = (kt == 2 * qt);
            const bool diagB = (kt == last);

            // QK^T: each K fragment read feeds BOTH q-groups.
            floatx4 sa[4], sb[4];
#pragma unroll
            for (int c = 0; c < 4; ++c) {
                short8 kf0 = *(const short8*)&Ks[c * 16 + ln][(g ^ sw) * 8];
                short8 kf1 = *(const short8*)&Ks[c * 16 + ln][((4 + g) ^ sw) * 8];
                floatx4 z = {0.f, 0.f, 0.f, 0.f};
                if (a_act) {
                    floatx4 za = __builtin_amdgcn_mfma_f32_16x16x32_bf16(kf0, aq0a, z, 0, 0, 0);
                    sa[c] = __builtin_amdgcn_mfma_f32_16x16x32_bf16(kf1, aq1a, za, 0, 0, 0);
                }
                floatx4 zb = __builtin_amdgcn_mfma_f32_16x16x32_bf16(kf0, aq0b, z, 0, 0, 0);
                sb[c] = __builtin_amdgcn_mfma_f32_16x16x32_bf16(kf1, aq1b, zb, 0, 0, 0);
            }

            // softmax (exp2-domain) + pack into Pw; group a rows [ln], b rows [16+ln]
            if (a_act) {
#pragma unroll
                for (int c = 0; c < 4; ++c) {
                    float pv[4];
#pragma unroll
                    for (int r = 0; r < 4; ++r) {
                        float e = __builtin_amdgcn_exp2f(sa[c][r]);
                        if (diagA && (k0 + c * 16 + g * 4 + r > qlA)) e = 0.f;
                        pv[r] = e;
                    }
                    uint2 pk;
                    pk.x = pk_bf2(pv[0], pv[1]);
                    pk.y = pk_bf2(pv[2], pv[3]);
                    *(uint2*)&Pw[w][ln][((2 * c + (g >> 1)) ^ sw) * 8 + (g & 1) * 4] = pk;
                }
            }
#pragma unroll
            for (int c = 0; c < 4; ++c) {
                float pv[4];
#pragma unroll
                for (int r = 0; r < 4; ++r) {
                    float e = __builtin_amdgcn_exp2f(sb[c][r]);
                    if (diagB && (k0 + c * 16 + g * 4 + r > qlB)) e = 0.f;
                    pv[r] = e;
                }
                uint2 pk;
                pk.x = pk_bf2(pv[0], pv[1]);
                pk.y = pk_bf2(pv[2], pv[3]);
                *(uint2*)&Pw[w][16 + ln][((2 * c + (g >> 1)) ^ sw) * 8 + (g & 1) * 4] = pk;
            }

            short8 pa0a, pa1a;
            if (a_act) {
                pa0a = *(const short8*)&Pw[w][ln][(g ^ sw) * 8];
                pa1a = *(const short8*)&Pw[w][ln][((4 + g) ^ sw) * 8];
            }
            short8 pa0b = *(const short8*)&Pw[w][16 + ln][(g ^ sw) * 8];
            short8 pa1b = *(const short8*)&Pw[w][16 + ln][((4 + g) ^ sw) * 8];

            // PV: each V fragment read feeds BOTH q-groups.
#pragma unroll
            for (int n = 0; n < 3; ++n) {
                short8 vb0 = *(const short8*)&Vs[n * 16 + ln][(g ^ sw) * 8];
                short8 vb1 = *(const short8*)&Vs[n * 16 + ln][((4 + g) ^ sw) * 8];
                if (a_act) {
                    floatx4 acc = (n == 0) ? oa0 : (n == 1) ? oa1 : oa2;
                    acc = __builtin_amdgcn_mfma_f32_16x16x32_bf16(pa0a, vb0, acc, 0, 0, 0);
                    acc = __builtin_amdgcn_mfma_f32_16x16x32_bf16(pa1a, vb1, acc, 0, 0, 0);
                    if (n == 0) oa0 = acc; else if (n == 1) oa1 = acc; else oa2 = acc;
                }
                floatx4 accb = (n == 0) ? ob0 : (n == 1) ? ob1 : ob2;
                accb = __builtin_amdgcn_mfma_f32_16x16x32_bf16(pa0b, vb0, accb, 0, 0, 0);
                accb = __builtin_amdgcn_mfma_f32_16x16x32_bf16(pa1b, vb1, accb, 0, 0, 0);
                if (n == 0) ob0 = accb; else if (n == 1) ob1 = accb; else ob2 = accb;
            }
            if (a_act) {
                oa3 = __builtin_amdgcn_mfma_f32_16x16x32_bf16(pa0a, vone, oa3, 0, 0, 0);
                oa3 = __builtin_amdgcn_mfma_f32_16x16x32_bf16(pa1a, vone, oa3, 0, 0, 0);
            }
            ob3 = __builtin_amdgcn_mfma_f32_16x16x32_bf16(pa0b, vone, ob3, 0, 0, 0);
            ob3 = __builtin_amdgcn_mfma_f32_16x16x32_bf16(pa1b, vone, ob3, 0, 0, 0);
        }

        if (ln == 0) {
            *(floatx4*)&l_s[w][g * 4] = oa3;          // per-wave region, no barrier
            *(floatx4*)&l_s[w][16 + g * 4] = ob3;
        }
        floatx4 l4a = *(const floatx4*)&l_s[w][g * 4];
        floatx4 l4b = *(const floatx4*)&l_s[w][16 + g * 4];
#pragma unroll
        for (int r = 0; r < 4; ++r) {
            float invA = 1.0f / l4a[r];
            int t = q0 + w * 16 + g * 4 + r;
            unsigned short* dst = ctx + (size_t)(b * TT + t) * CC + h * HD;
            dst[ln] = f2bf(oa0[r] * invA);
            dst[16 + ln] = f2bf(oa1[r] * invA);
            dst[32 + ln] = f2bf(oa2[r] * invA);
            float invB = 1.0f / l4b[r];
            unsigned short* dstB = dst + (size_t)64 * CC;
            dstB[ln] = f2bf(ob0[r] * invB);
            dstB[16 + ln] = f2bf(ob1[r] * invB);
            dstB[32 + ln] = f2bf(ob2[r] * invB);
        }
    }
}

extern "C" void kernel_launch(void* const* d_in, const int* in_sizes, int n_in,
                              void* d_out, int out_size, void* d_ws, size_t ws_size,
                              hipStream_t stream) {
    const float* hs = (const float*)d_in[0];
    const float* amask = (const float*)d_in[1];
    const float* Wq = (const float*)d_in[2];
    const float* bq = (const float*)d_in[3];
    const float* Wk = (const float*)d_in[4];
    const float* bk = (const float*)d_in[5];
    const float* Wv = (const float*)d_in[6];
    const float* bv = (const float*)d_in[7];
    const float* Wo = (const float*)d_in[8];
    const float* bo = (const float*)d_in[9];

    const size_t NELEM = (size_t)BB * TT * CC;  // 6291456
    const size_t WELEM = (size_t)CC * CC;       // 589824
    unsigned short* hb  = (unsigned short*)d_ws;
    unsigned short* qbuf = hb + NELEM;
    unsigned short* kbuf = qbuf + NELEM;
    unsigned short* vtb = kbuf + NELEM;   // bf16 [B,H,D,T]
    unsigned short* ctxb = vtb + NELEM;
    unsigned short* wqb = ctxb + NELEM;   // wq/wk/wv contiguous = stacked [2304][768]
    unsigned short* wkb = wqb + WELEM;
    unsigned short* wvb = wkb + WELEM;
    unsigned short* wob = wvb + WELEM;
    float2* ropetab = (float2*)(wob + WELEM);  // [2048][24]

    cast_hs<<<NELEM / 1024, 256, 0, stream>>>(hs, hb);
    dim3 wgrid(WELEM / 1024, 4);
    cast_w4<<<wgrid, 256, 0, stream>>>(Wq, Wk, Wv, Wo, wqb, wkb, wvb, wob);
    rope_table<<<(TT * (HD / 2)) / 256, 256, 0, stream>>>(ropetab);

    gemm_mfma<1><<<18 * 64, 256, 0, stream>>>(hb, wqb, bq, bk, bv, qbuf, kbuf, vtb);

    int rope_total = BB * TT * NHD * 3;  // 8 pairs per thread
    rope_bf<<<rope_total / 256, 256, 0, stream>>>(qbuf, kbuf, ropetab);

    attn_kernel<<<512, 256, 0, stream>>>(qbuf, kbuf, vtb, amask, ctxb);

    gemm_mfma<0><<<6 * 64, 256, 0, stream>>>(ctxb, wob, bo, nullptr, nullptr,
                                             (float*)d_out, nullptr, nullptr);
}

// Round 12
// 220.392 us; speedup vs baseline: 1.1073x; 1.0038x over previous
//
#include <hip/hip_runtime.h>
#include <hip/hip_bf16.h>
#include <math.h>

#define BB 4
#define TT 2048
#define CC 768
#define NHD 16
#define HD 48
#define NQT2 16  // TT/128

typedef __hip_bfloat16 bf16;
typedef __attribute__((ext_vector_type(8))) short short8;
typedef __attribute__((ext_vector_type(4))) float floatx4;

__device__ __forceinline__ unsigned short f2bf(float x) {
    bf16 h = __float2bfloat16(x);
    return *(unsigned short*)&h;
}
__device__ __forceinline__ float bfu2f(unsigned short u) {
    return __uint_as_float(((unsigned)u) << 16);
}

// async global->LDS, 16B per lane; LDS dest = wave-uniform base + lane*16
__device__ __forceinline__ void gl_lds16(const void* g, void* s) {
    __builtin_amdgcn_global_load_lds((const __attribute__((address_space(1))) void*)g,
                                     (__attribute__((address_space(3))) void*)s, 16, 0, 0);
}

// pack two fp32 -> packed bf16 pair (round-half-up; inputs are probabilities >= 0)
__device__ __forceinline__ unsigned int pk_bf2(float a, float b) {
    unsigned int ua = __float_as_uint(a) + 0x8000u;
    unsigned int ub = __float_as_uint(b) + 0x8000u;
    return __builtin_amdgcn_perm(ub, ua, 0x07060302);
}

// hot-loop barrier: make LDS writes visible, do NOT drain vmcnt -- register
// global loads (K/V prefetch) stay in flight across the barrier.
#define HOT_BARRIER() asm volatile("s_waitcnt lgkmcnt(0)\n\ts_barrier" ::: "memory")

// ---------- fp32 -> bf16 casts ----------
__global__ __launch_bounds__(256) void cast_hs(const float* __restrict__ src,
                                               unsigned short* __restrict__ dst) {
    int i = (blockIdx.x * 256 + threadIdx.x) * 4;
    float4 v = *(const float4*)(src + i);
    ushort4 p;
    p.x = f2bf(v.x); p.y = f2bf(v.y); p.z = f2bf(v.z); p.w = f2bf(v.w);
    *(ushort4*)(dst + i) = p;
}

__global__ __launch_bounds__(256) void cast_w4(const float* __restrict__ s0, const float* __restrict__ s1,
                                               const float* __restrict__ s2, const float* __restrict__ s3,
                                               unsigned short* __restrict__ d0, unsigned short* __restrict__ d1,
                                               unsigned short* __restrict__ d2, unsigned short* __restrict__ d3) {
    const float* s; unsigned short* d;
    switch (blockIdx.y) {
        case 0: s = s0; d = d0; break;
        case 1: s = s1; d = d1; break;
        case 2: s = s2; d = d2; break;
        default: s = s3; d = d3; break;
    }
    int i = (blockIdx.x * 256 + threadIdx.x) * 4;
    float4 v = *(const float4*)(s + i);
    ushort4 p;
    p.x = f2bf(v.x); p.y = f2bf(v.y); p.z = f2bf(v.z); p.w = f2bf(v.w);
    *(ushort4*)(d + i) = p;
}

// ---------- RoPE sincos table: tab[t][p] = {cos, sin}, p in [0,24) ----------
__global__ __launch_bounds__(256) void rope_table(float2* __restrict__ tab) {
    int idx = blockIdx.x * 256 + threadIdx.x;  // over 2048*24
    int t = idx / 24, p = idx % 24;
    float inv_freq = powf(10000.0f, -((float)(2 * p) / (float)HD));
    float ang = (float)t * inv_freq;
    float sn, cs;
    sincosf(ang, &sn, &cs);
    tab[idx] = make_float2(cs, sn);
}

// ---------- bf16 MFMA NT-GEMM, BK=64, lds-direct staging with XOR-swizzle ----------
// MODE 1 only now: fused QKV N=2304 (NXB=18). (MODE 0 replaced by gemm_out.)
template <int MODE>
__global__ __launch_bounds__(256) void gemm_mfma(const unsigned short* __restrict__ A,
                                                 const unsigned short* __restrict__ Bw,
                                                 const float* __restrict__ b0p,
                                                 const float* __restrict__ b1p,
                                                 const float* __restrict__ b2p,
                                                 void* __restrict__ out0,
                                                 void* __restrict__ out1,
                                                 void* __restrict__ out2) {
    __shared__ __align__(16) unsigned short As[128][64];
    __shared__ __align__(16) unsigned short Bs[128][64];
    const int tid = threadIdx.x;
    const int w = tid >> 6, lane = tid & 63;
    const int quad = lane >> 4, ln = lane & 15;
    const int wr = w >> 1, wc = w & 1;

    const int NXB = (MODE == 1) ? 18 : 6;
    const int bx = blockIdx.x;
    const int xcd = bx & 7, slot = bx >> 3;
    const int n0 = (slot % NXB) * 128;
    const int m0 = ((slot / NXB) * 8 + xcd) * 128;

    const int srow = lane >> 3;
    const int ssw = ((lane & 7) ^ srow) * 8;
    const unsigned short* agp[4];
    const unsigned short* bgp[4];
    void* asl[4];
    void* bsl[4];
#pragma unroll
    for (int i = 0; i < 4; ++i) {
        const int R = i * 32 + w * 8;
        agp[i] = A + (size_t)(m0 + R + srow) * CC + ssw;
        bgp[i] = Bw + (size_t)(n0 + R + srow) * CC + ssw;
        asl[i] = &As[R][0];
        bsl[i] = &Bs[R][0];
    }

    floatx4 acc[4][4];
#pragma unroll
    for (int mi = 0; mi < 4; ++mi)
#pragma unroll
        for (int ni = 0; ni < 4; ++ni) acc[mi][ni] = (floatx4){0.f, 0.f, 0.f, 0.f};

    const int ps0 = (quad ^ (ln & 7)) * 8;

    for (int k0 = 0; k0 < CC; k0 += 64) {
        __syncthreads();
#pragma unroll
        for (int i = 0; i < 4; ++i) {
            gl_lds16(agp[i] + k0, asl[i]);
            gl_lds16(bgp[i] + k0, bsl[i]);
        }
        __syncthreads();
#pragma unroll
        for (int kh = 0; kh < 2; ++kh) {
            const int ps = ps0 ^ (kh * 32);
            short8 af[4], bfr[4];
#pragma unroll
            for (int mi = 0; mi < 4; ++mi)
                af[mi] = *(const short8*)&As[wr * 64 + mi * 16 + ln][ps];
#pragma unroll
            for (int ni = 0; ni < 4; ++ni)
                bfr[ni] = *(const short8*)&Bs[wc * 64 + ni * 16 + ln][ps];
#pragma unroll
            for (int mi = 0; mi < 4; ++mi)
#pragma unroll
                for (int ni = 0; ni < 4; ++ni)
                    acc[mi][ni] = __builtin_amdgcn_mfma_f32_16x16x32_bf16(af[mi], bfr[ni], acc[mi][ni], 0, 0, 0);
        }
    }

    if (MODE == 0) {
        float* outf = (float*)out0;
        float bv[4];
#pragma unroll
        for (int ni = 0; ni < 4; ++ni) bv[ni] = b0p[n0 + wc * 64 + ni * 16 + ln];
#pragma unroll
        for (int mi = 0; mi < 4; ++mi)
#pragma unroll
            for (int r = 0; r < 4; ++r) {
                size_t row = m0 + wr * 64 + mi * 16 + quad * 4 + r;
#pragma unroll
                for (int ni = 0; ni < 4; ++ni)
                    outf[row * CC + n0 + wc * 64 + ni * 16 + ln] = acc[mi][ni][r] + bv[ni];
            }
    } else {
        const int seg = n0 / CC;
        const int nl0 = n0 - seg * CC;
        const float* bp = (seg == 0) ? b0p : (seg == 1) ? b1p : b2p;
        float bv[4];
#pragma unroll
        for (int ni = 0; ni < 4; ++ni) bv[ni] = bp[nl0 + wc * 64 + ni * 16 + ln];

        if (seg < 2) {
            unsigned short* outb = (unsigned short*)(seg == 0 ? out0 : out1);
#pragma unroll
            for (int mi = 0; mi < 4; ++mi)
#pragma unroll
                for (int r = 0; r < 4; ++r) {
                    size_t row = m0 + wr * 64 + mi * 16 + quad * 4 + r;
#pragma unroll
                    for (int ni = 0; ni < 4; ++ni)
                        outb[row * CC + nl0 + wc * 64 + ni * 16 + ln] = f2bf(acc[mi][ni][r] + bv[ni]);
                }
        } else {
            unsigned short* outb = (unsigned short*)out2;
            const int b = m0 >> 11;
#pragma unroll
            for (int ni = 0; ni < 4; ++ni) {
                int col = nl0 + wc * 64 + ni * 16 + ln;
                int h = col / HD, d = col % HD;
                size_t base = (size_t)((b * NHD + h) * HD + d) * TT;
#pragma unroll
                for (int mi = 0; mi < 4; ++mi) {
                    int t = (m0 & 2047) + wr * 64 + mi * 16 + quad * 4;
                    ushort4 pk;
                    pk.x = f2bf(acc[mi][ni][0] + bv[ni]);
                    pk.y = f2bf(acc[mi][ni][1] + bv[ni]);
                    pk.z = f2bf(acc[mi][ni][2] + bv[ni]);
                    pk.w = f2bf(acc[mi][ni][3] + bv[ni]);
                    *(ushort4*)(outb + base + t) = pk;
                }
            }
        }
    }
}

// ---------- output projection GEMM: 128x64 tiles, grid 768 = 3.0 blocks/CU ----------
// Same verified machinery as gemm_mfma (2-barrier K-loop, gl_lds16 staging,
// XOR swizzle), re-tiled: the old MODE-0 grid was 64x6 = 384 blocks =
// 1.5 blocks/CU -> half the CUs ran 2 sequential tiles while half idled.
// 128x64 tiles give 64x12 = 768 blocks = exactly 3/CU, uniform finish.
// Waves 4x1 over rows: wave w owns rows w*32..w*32+31, all 64 cols; acc[2][4].
// XCD pinning: the 12 n-blocks of one A row-band share an XCD (A stays
// L2-resident despite the 2x nominal A-redundancy of narrower tiles).
__global__ __launch_bounds__(256) void gemm_out(const unsigned short* __restrict__ A,
                                                const unsigned short* __restrict__ Bw,
                                                const float* __restrict__ bias,
                                                float* __restrict__ out) {
    __shared__ __align__(16) unsigned short As[128][64];
    __shared__ __align__(16) unsigned short Bs[64][64];
    const int tid = threadIdx.x;
    const int w = tid >> 6, lane = tid & 63;
    const int quad = lane >> 4, ln = lane & 15;

    const int bx = blockIdx.x;
    const int xcd = bx & 7, slot = bx >> 3;      // slot in [0,96)
    const int n0 = (slot % 12) * 64;
    const int m0 = ((slot / 12) * 8 + xcd) * 128;

    const int srow = lane >> 3;
    const int ssw = ((lane & 7) ^ srow) * 8;
    const unsigned short* agp[4];
    const unsigned short* bgp[2];
    void* asl[4];
    void* bsl[2];
#pragma unroll
    for (int i = 0; i < 4; ++i) {
        const int R = i * 32 + w * 8;            // rows 0..127 w/ srow
        agp[i] = A + (size_t)(m0 + R + srow) * CC + ssw;
        asl[i] = &As[R][0];
    }
#pragma unroll
    for (int i = 0; i < 2; ++i) {
        const int R = i * 32 + w * 8;            // rows 0..63 w/ srow
        bgp[i] = Bw + (size_t)(n0 + R + srow) * CC + ssw;
        bsl[i] = &Bs[R][0];
    }

    floatx4 acc[2][4];
#pragma unroll
    for (int mi = 0; mi < 2; ++mi)
#pragma unroll
        for (int ni = 0; ni < 4; ++ni) acc[mi][ni] = (floatx4){0.f, 0.f, 0.f, 0.f};

    const int ps0 = (quad ^ (ln & 7)) * 8;

    for (int k0 = 0; k0 < CC; k0 += 64) {
        __syncthreads();
#pragma unroll
        for (int i = 0; i < 4; ++i) gl_lds16(agp[i] + k0, asl[i]);
#pragma unroll
        for (int i = 0; i < 2; ++i) gl_lds16(bgp[i] + k0, bsl[i]);
        __syncthreads();
#pragma unroll
        for (int kh = 0; kh < 2; ++kh) {
            const int ps = ps0 ^ (kh * 32);
            short8 af[2], bfr[4];
#pragma unroll
            for (int mi = 0; mi < 2; ++mi)
                af[mi] = *(const short8*)&As[w * 32 + mi * 16 + ln][ps];
#pragma unroll
            for (int ni = 0; ni < 4; ++ni)
                bfr[ni] = *(const short8*)&Bs[ni * 16 + ln][ps];
#pragma unroll
            for (int mi = 0; mi < 2; ++mi)
#pragma unroll
                for (int ni = 0; ni < 4; ++ni)
                    acc[mi][ni] = __builtin_amdgcn_mfma_f32_16x16x32_bf16(af[mi], bfr[ni], acc[mi][ni], 0, 0, 0);
        }
    }

    float bv[4];
#pragma unroll
    for (int ni = 0; ni < 4; ++ni) bv[ni] = bias[n0 + ni * 16 + ln];
#pragma unroll
    for (int mi = 0; mi < 2; ++mi)
#pragma unroll
        for (int r = 0; r < 4; ++r) {
            size_t row = m0 + w * 32 + mi * 16 + quad * 4 + r;
#pragma unroll
            for (int ni = 0; ni < 4; ++ni)
                out[row * CC + n0 + ni * 16 + ln] = acc[mi][ni][r] + bv[ni];
        }
}

// RoPE in-place via precomputed table, vectorized (8 pairs/thread).
__global__ __launch_bounds__(256) void rope_bf(unsigned short* __restrict__ q,
                                               unsigned short* __restrict__ k,
                                               const float2* __restrict__ tab) {
    int idx = blockIdx.x * blockDim.x + threadIdx.x;  // over B*T*H*3
    const int HALF = HD / 2;
    int p8 = idx % 3;
    int rest = idx / 3;
    int h = rest % NHD;
    int n = rest / NHD;        // b*T + t
    int t = n & (TT - 1);
    const float QSC = 0.14433756729740643f * 1.4426950408889634f;
    size_t base = (size_t)n * CC + h * HD + p8 * 8;
    const float2* tp = tab + t * HALF + p8 * 8;

    short8 q1 = *(const short8*)(q + base);
    short8 q2 = *(const short8*)(q + base + HALF);
    short8 k1 = *(const short8*)(k + base);
    short8 k2 = *(const short8*)(k + base + HALF);
    short8 r1, r2, s1, s2;
#pragma unroll
    for (int jj = 0; jj < 8; ++jj) {
        float2 cssn = tp[jj];
        float cs = cssn.x, sn = cssn.y;
        float a = bfu2f((unsigned short)q1[jj]), bb = bfu2f((unsigned short)q2[jj]);
        r1[jj] = (short)f2bf((a * cs - bb * sn) * QSC);
        r2[jj] = (short)f2bf((bb * cs + a * sn) * QSC);
        float c2 = bfu2f((unsigned short)k1[jj]), d2 = bfu2f((unsigned short)k2[jj]);
        s1[jj] = (short)f2bf(c2 * cs - d2 * sn);
        s2[jj] = (short)f2bf(d2 * cs + c2 * sn);
    }
    *(short8*)(q + base) = r1;
    *(short8*)(q + base + HALF) = r2;
    *(short8*)(k + base) = s1;
    *(short8*)(k + base + HALF) = s2;
}

// MFMA flash attention, exp2-domain, fixed softmax reference (m=0).
// Harness-verified session best (round 4/11, ~56us attn): 128 q-rows per
// block (two 64-row groups a/b per wave: each wave owns 32 q-rows), so every
// K/V fragment read from LDS feeds TWO MFMAs. K and V live in LDS
// (XOR-swizzled, [64] cols); both barriers are lgkm-only so the K/V register
// prefetch stays in flight. Q direct from global. Grid 512 = 64 (b,h) x 8
// pairs; pair schedule (qt, 15-qt) = exactly 34 k-steps per block;
// XCD-pinned -> exactly 2 blocks/CU, zero tail. launch_bounds(256,2):
// 256-VGPR cap eliminates the spill failure mode.
__global__ __launch_bounds__(256, 2) void attn_kernel(const unsigned short* __restrict__ qb,
                                                      const unsigned short* __restrict__ kb,
                                                      const unsigned short* __restrict__ vt,
                                                      const float* __restrict__ amask,
                                                      unsigned short* __restrict__ ctx) {
    const int bx = blockIdx.x;
    const int xcd = bx & 7;
    const int rem = bx >> 3;                // [0,64)
    const int pair = rem & 7;
    const int j = ((rem >> 3) << 3) | xcd;  // (b,h) group, grouped per XCD
    const int b = j >> 4, h = j & 15;
    const int tid = threadIdx.x;
    const int w = tid >> 6, lane = tid & 63;
    const int g = lane >> 4, ln = lane & 15;
    const int sw = ln & 7;

    __shared__ __align__(16) unsigned short Ks[64][64];
    __shared__ __align__(16) unsigned short Vs[48][64];
    __shared__ __align__(16) unsigned short Pw[4][32][64];
    __shared__ __align__(16) float l_s[4][32];

    const short8 z8 = {0, 0, 0, 0, 0, 0, 0, 0};
    const short8 ones8 = {0x3F80, 0x3F80, 0x3F80, 0x3F80, 0x3F80, 0x3F80, 0x3F80, 0x3F80};

    // zero Ks pad units 6,7 (XOR-swizzled) once; unit-6 elem 0 = mask slot
    // (rewritten each step), elems 1..7 and unit 7 stay 0.
    if (tid < 128) {
        int rr = tid >> 1, half = tid & 1;
        *(short8*)&Ks[rr][((6 + half) ^ (rr & 7)) * 8] = z8;
    }

    // K stage: 64 rows x 6 units (48 cols). V stage: 48 rows x 8 units (64 cols).
    const int ck1 = tid + 256;
    const int rK0 = tid / 6, sK0 = tid % 6;
    const int rK1 = ck1 / 6, sK1 = ck1 % 6;
    const int swK0 = (sK0 ^ (rK0 & 7)) * 8;
    const int swK1 = (sK1 ^ (rK1 & 7)) * 8;
    const int rV0 = tid >> 3, sV0 = tid & 7;   // rows 0..31
    const int rV1 = rV0 + 32;                  // tid<128: rows 32..47
    const int swV0 = (sV0 ^ (rV0 & 7)) * 8;
    const int swV1 = (sV0 ^ (rV1 & 7)) * 8;

    const unsigned short* kbase0 = kb + (size_t)(b * TT + rK0) * CC + h * HD + sK0 * 8;
    const unsigned short* kbase1 = kb + (size_t)(b * TT + rK1) * CC + h * HD + sK1 * 8;
    const unsigned short* vbase0 = vt + ((size_t)((b * NHD + h) * HD) + rV0) * TT + sV0 * 8;
    const unsigned short* vbase1 = vbase0 + (size_t)32 * TT;
    const float* mbase = amask + b * TT + (tid & 63);
    const float MBS = -10000.0f * 1.4426950408889634f;
    const int mcol = (6 ^ (lane & 7)) * 8;     // swizzled mask slot (row = lane)
    const short8 vone = (ln == 0) ? ones8 : z8;  // ones-column B-frag (l accumulator)

    for (int rep = 0; rep < 2; ++rep) {
        const int qt = rep ? (NQT2 - 1 - pair) : pair;
        const int q0 = qt * 128;
        const int last = 2 * qt + 1;

        // Q fragments straight from global, two row-groups per wave.
        const unsigned short* qrA = qb + (size_t)(b * TT + q0 + w * 16 + ln) * CC + h * HD;
        const unsigned short* qrB = qrA + (size_t)64 * CC;
        short8 aq0a = *(const short8*)(qrA + g * 8);
        short8 aq0b = *(const short8*)(qrB + g * 8);
        short8 aq1a, aq1b;
        if (g < 2) {
            aq1a = *(const short8*)(qrA + 32 + g * 8);
            aq1b = *(const short8*)(qrB + 32 + g * 8);
        } else {
            aq1a = z8; aq1b = z8;
            if (g == 2) { aq1a[0] = (short)0x3F80; aq1b[0] = (short)0x3F80; }
        }

        const unsigned short* kp0 = kbase0;
        const unsigned short* kp1 = kbase1;
        const unsigned short* vp0 = vbase0;
        const unsigned short* vp1 = vbase1;
        const float* mp = mbase;

        short8 kr0, kr1, vr0, vr1;
        float mr = 1.0f;
        kr0 = *(const short8*)kp0;
        vr0 = *(const short8*)vp0;
        if (tid < 128) { kr1 = *(const short8*)kp1; vr1 = *(const short8*)vp1; }
        if (tid < 64) mr = *mp;

        const int qlA = q0 + w * 16 + ln;
        const int qlB = qlA + 64;
        floatx4 oa0 = {0.f, 0.f, 0.f, 0.f}, oa1 = oa0, oa2 = oa0, oa3 = oa0;
        floatx4 ob0 = oa0, ob1 = oa0, ob2 = oa0, ob3 = oa0;

        for (int kt = 0; kt <= last; ++kt) {
            HOT_BARRIER();   // prior step's LDS reads complete
            *(short8*)&Ks[rK0][swK0] = kr0;
            *(short8*)&Vs[rV0][swV0] = vr0;
            if (tid < 128) {
                *(short8*)&Ks[rK1][swK1] = kr1;
                *(short8*)&Vs[rV1][swV1] = vr1;
            }
            if (tid < 64) Ks[lane][mcol] = f2bf((1.0f - mr) * MBS);
            HOT_BARRIER();   // writes visible; vmcnt NOT drained

            if (kt < last) {
                kp0 += (size_t)64 * CC; kr0 = *(const short8*)kp0;
                vp0 += 64;              vr0 = *(const short8*)vp0;
                if (tid < 128) {
                    kp1 += (size_t)64 * CC; kr1 = *(const short8*)kp1;
                    vp1 += 64;              vr1 = *(const short8*)vp1;
                }
                if (tid < 64) { mp += 64; mr = *mp; }
            }

            const int k0 = kt * 64;
            const bool a_act = (kt <= 2 * qt);
            const bool diagA = (kt == 2 * qt);
            const bool diagB = (kt == last);

            // QK^T: each K fragment read feeds BOTH q-groups.
            floatx4 sa[4], sb[4];
#pragma unroll
            for (int c = 0; c < 4; ++c) {
                short8 kf0 = *(const short8*)&Ks[c * 16 + ln][(g ^ sw) * 8];
                short8 kf1 = *(const short8*)&Ks[c * 16 + ln][((4 + g) ^ sw) * 8];
                floatx4 z = {0.f, 0.f, 0.f, 0.f};
                if (a_act) {
                    floatx4 za = __builtin_amdgcn_mfma_f32_16x16x32_bf16(kf0, aq0a, z, 0, 0, 0);
                    sa[c] = __builtin_amdgcn_mfma_f32_16x16x32_bf16(kf1, aq1a, za, 0, 0, 0);
                }
                floatx4 zb = __builtin_amdgcn_mfma_f32_16x16x32_bf16(kf0, aq0b, z, 0, 0, 0);
                sb[c] = __builtin_amdgcn_mfma_f32_16x16x32_bf16(kf1, aq1b, zb, 0, 0, 0);
            }

            // softmax (exp2-domain) + pack into Pw; group a rows [ln], b rows [16+ln]
            if (a_act) {
#pragma unroll
                for (int c = 0; c < 4; ++c) {
                    float pv[4];
#pragma unroll
                    for (int r = 0; r < 4; ++r) {
                        float e = __builtin_amdgcn_exp2f(sa[c][r]);
                        if (diagA && (k0 + c * 16 + g * 4 + r > qlA)) e = 0.f;
                        pv[r] = e;
                    }
                    uint2 pk;
                    pk.x = pk_bf2(pv[0], pv[1]);
                    pk.y = pk_bf2(pv[2], pv[3]);
                    *(uint2*)&Pw[w][ln][((2 * c + (g >> 1)) ^ sw) * 8 + (g & 1) * 4] = pk;
                }
            }
#pragma unroll
            for (int c = 0; c < 4; ++c) {
                float pv[4];
#pragma unroll
                for (int r = 0; r < 4; ++r) {
                    float e = __builtin_amdgcn_exp2f(sb[c][r]);
                    if (diagB && (k0 + c * 16 + g * 4 + r > qlB)) e = 0.f;
                    pv[r] = e;
                }
                uint2 pk;
                pk.x = pk_bf2(pv[0], pv[1]);
                pk.y = pk_bf2(pv[2], pv[3]);
                *(uint2*)&Pw[w][16 + ln][((2 * c + (g >> 1)) ^ sw) * 8 + (g & 1) * 4] = pk;
            }

            short8 pa0a, pa1a;
            if (a_act) {
                pa0a = *(const short8*)&Pw[w][ln][(g ^ sw) * 8];
                pa1a = *(const short8*)&Pw[w][ln][((4 + g) ^ sw) * 8];
            }
            short8 pa0b = *(const short8*)&Pw[w][16 + ln][(g ^ sw) * 8];
            short8 pa1b = *(const short8*)&Pw[w][16 + ln][((4 + g) ^ sw) * 8];

            // PV: each V fragment read feeds BOTH q-groups.
#pragma unroll
            for (int n = 0; n < 3; ++n) {
                short8 vb0 = *(const short8*)&Vs[n * 16 + ln][(g ^ sw) * 8];
                short8 vb1 = *(const short8*)&Vs[n * 16 + ln][((4 + g) ^ sw) * 8];
                if (a_act) {
                    floatx4 acc = (n == 0) ? oa0 : (n == 1) ? oa1 : oa2;
                    acc = __builtin_amdgcn_mfma_f32_16x16x32_bf16(pa0a, vb0, acc, 0, 0, 0);
                    acc = __builtin_amdgcn_mfma_f32_16x16x32_bf16(pa1a, vb1, acc, 0, 0, 0);
                    if (n == 0) oa0 = acc; else if (n == 1) oa1 = acc; else oa2 = acc;
                }
                floatx4 accb = (n == 0) ? ob0 : (n == 1) ? ob1 : ob2;
                accb = __builtin_amdgcn_mfma_f32_16x16x32_bf16(pa0b, vb0, accb, 0, 0, 0);
                accb = __builtin_amdgcn_mfma_f32_16x16x32_bf16(pa1b, vb1, accb, 0, 0, 0);
                if (n == 0) ob0 = accb; else if (n == 1) ob1 = accb; else ob2 = accb;
            }
            if (a_act) {
                oa3 = __builtin_amdgcn_mfma_f32_16x16x32_bf16(pa0a, vone, oa3, 0, 0, 0);
                oa3 = __builtin_amdgcn_mfma_f32_16x16x32_bf16(pa1a, vone, oa3, 0, 0, 0);
            }
            ob3 = __builtin_amdgcn_mfma_f32_16x16x32_bf16(pa0b, vone, ob3, 0, 0, 0);
            ob3 = __builtin_amdgcn_mfma_f32_16x16x32_bf16(pa1b, vone, ob3, 0, 0, 0);
        }

        if (ln == 0) {
            *(floatx4*)&l_s[w][g * 4] = oa3;          // per-wave region, no barrier
            *(floatx4*)&l_s[w][16 + g * 4] = ob3;
        }
        floatx4 l4a = *(const floatx4*)&l_s[w][g * 4];
        floatx4 l4b = *(const floatx4*)&l_s[w][16 + g * 4];
#pragma unroll
        for (int r = 0; r < 4; ++r) {
            float invA = 1.0f / l4a[r];
            int t = q0 + w * 16 + g * 4 + r;
            unsigned short* dst = ctx + (size_t)(b * TT + t) * CC + h * HD;
            dst[ln] = f2bf(oa0[r] * invA);
            dst[16 + ln] = f2bf(oa1[r] * invA);
            dst[32 + ln] = f2bf(oa2[r] * invA);
            float invB = 1.0f / l4b[r];
            unsigned short* dstB = dst + (size_t)64 * CC;
            dstB[ln] = f2bf(ob0[r] * invB);
            dstB[16 + ln] = f2bf(ob1[r] * invB);
            dstB[32 + ln] = f2bf(ob2[r] * invB);
        }
    }
}

extern "C" void kernel_launch(void* const* d_in, const int* in_sizes, int n_in,
                              void* d_out, int out_size, void* d_ws, size_t ws_size,
                              hipStream_t stream) {
    const float* hs = (const float*)d_in[0];
    const float* amask = (const float*)d_in[1];
    const float* Wq = (const float*)d_in[2];
    const float* bq = (const float*)d_in[3];
    const float* Wk = (const float*)d_in[4];
    const float* bk = (const float*)d_in[5];
    const float* Wv = (const float*)d_in[6];
    const float* bv = (const float*)d_in[7];
    const float* Wo = (const float*)d_in[8];
    const float* bo = (const float*)d_in[9];

    const size_t NELEM = (size_t)BB * TT * CC;  // 6291456
    const size_t WELEM = (size_t)CC * CC;       // 589824
    unsigned short* hb  = (unsigned short*)d_ws;
    unsigned short* qbuf = hb + NELEM;
    unsigned short* kbuf = qbuf + NELEM;
    unsigned short* vtb = kbuf + NELEM;   // bf16 [B,H,D,T]
    unsigned short* ctxb = vtb + NELEM;
    unsigned short* wqb = ctxb + NELEM;   // wq/wk/wv contiguous = stacked [2304][768]
    unsigned short* wkb = wqb + WELEM;
    unsigned short* wvb = wkb + WELEM;
    unsigned short* wob = wvb + WELEM;
    float2* ropetab = (float2*)(wob + WELEM);  // [2048][24]

    cast_hs<<<NELEM / 1024, 256, 0, stream>>>(hs, hb);
    dim3 wgrid(WELEM / 1024, 4);
    cast_w4<<<wgrid, 256, 0, stream>>>(Wq, Wk, Wv, Wo, wqb, wkb, wvb, wob);
    rope_table<<<(TT * (HD / 2)) / 256, 256, 0, stream>>>(ropetab);

    gemm_mfma<1><<<18 * 64, 256, 0, stream>>>(hb, wqb, bq, bk, bv, qbuf, kbuf, vtb);

    int rope_total = BB * TT * NHD * 3;  // 8 pairs per thread
    rope_bf<<<rope_total / 256, 256, 0, stream>>>(qbuf, kbuf, ropetab);

    attn_kernel<<<512, 256, 0, stream>>>(qbuf, kbuf, vtb, amask, ctxb);

    gemm_out<<<12 * 64, 256, 0, stream>>>(ctxb, wob, bo, (float*)d_out);
}